// Round 8
// baseline (504.686 us; speedup 1.0000x reference)
//
#include <hip/hip_runtime.h>
#include <hip/hip_bf16.h>
#include <hip/hip_fp16.h>

#define DD    128
#define VOCAB 2048
#define NRELS 7
#define NWF   (130 * 16384)   // W frag-layout elements: 128 kron + l + r chunks

typedef _Float16 f16;
typedef __attribute__((ext_vector_type(8))) _Float16 f16x8;
typedef __attribute__((ext_vector_type(4))) float    f32x4;

// flexible-dtype load: bf==1 -> bf16 storage, bf==0 -> f32 storage
__device__ __forceinline__ float lde(const void* p, size_t i, int bf) {
    if (bf) return (float)((const __hip_bfloat16*)p)[i];
    return ((const float*)p)[i];
}

// detect storage dtype by exponent-field sanity of Wv's first 64 uint16s
__device__ __forceinline__ int detect_bf(const unsigned short* wv) {
    int sane = 0;
    #pragma unroll
    for (int i = 0; i < 64; ++i) {
        unsigned e = (wv[i] >> 7) & 0xFFu;
        sane += (e >= 90u && e <= 160u) ? 1 : 0;
    }
    return sane == 64;
}

// counted vmcnt wait (T4). N is a compile-time literal.
template<int N>
__device__ __forceinline__ void wait_vmcnt() {
    asm volatile("s_waitcnt vmcnt(%0)" :: "n"(N) : "memory");
}

// ---------------------------------------------------------------------------
// prep_all: WvT transpose, W frag-major repack (NT stores: write-once data),
// biases, and zeroing the 128 split-K completion counters (graph-replay
// safety belt; reducers also self-re-arm). Frag layout:
// Wf[((i*8+n8)*4+t)*512 + ln*8 + e] = W[n8*16+(ln&15)][i*128+t*32+(ln>>4)*8+e]
// ---------------------------------------------------------------------------
__global__ void prep_all(const void* Wv, const void* bv,
                         const void* Wcps, const void* bcps,
                         const void* Wcpst, const void* bcpst,
                         const void* Wcpr, const void* bcpr,
                         const void* Wcprt, const void* bcprt,
                         const void* Wsm, const void* bsm,
                         f16* __restrict__ WvT, f16* __restrict__ Wext, f16* __restrict__ Wfin,
                         float* __restrict__ bias_lvl, float* __restrict__ bias_fin,
                         float* __restrict__ Wsm_f, float* __restrict__ bsm_f,
                         unsigned* __restrict__ cnt)
{
    const int bf = detect_bf((const unsigned short*)Wv);
    const int b = blockIdx.x;
    const int tid = threadIdx.x;

    if (b < 64) {                     // ---- WvT transpose ----
        __shared__ float tile[64][65];
        int vt = b >> 1, dt = b & 1;
        int tx = tid & 63, ty = tid >> 6;
        for (int yy = ty; yy < 64; yy += 4)
            tile[yy][tx] = lde(Wv, (size_t)(dt * 64 + yy) * VOCAB + vt * 64 + tx, bf);
        __syncthreads();
        for (int yy = ty; yy < 64; yy += 4) {
            int v = vt * 64 + yy, d = dt * 64 + tx;
            __builtin_nontemporal_store((f16)(tile[tx][yy] + lde(bv, d, bf)),
                                        &WvT[(size_t)v * DD + d]);
        }
        return;
    }
    if (b >= 2144) {                  // ---- biases + softmax weights + counters ----
        if (tid < 128) {
            bias_lvl[tid] = lde(bcps, tid, bf) + lde(bcpst, tid, bf);
            cnt[tid] = 0u;
        } else if (tid < 256) {
            bias_fin[tid - 128] = lde(bcpr, tid - 128, bf) + lde(bcprt, tid - 128, bf);
        }
        for (int o = tid; o < NRELS * DD; o += 256) Wsm_f[o] = lde(Wsm, o, bf);
        if (tid < NRELS) bsm_f[tid] = lde(bsm, tid, bf);
        return;
    }
    // ---- W frag repack ----
    const int bb    = b - 64;
    const int which = bb / 1040;      // 0: ext, 1: fin
    const int rem   = bb - which * 1040;
    const int i     = rem >> 3;       // 0..129
    const int n8    = rem & 7;
    const void* Wt = which ? (const void*)Wcprt : (const void*)Wcpst;
    const void* Ws = which ? (const void*)Wcpr  : (const void*)Wcps;
    f16* dst = which ? Wfin : Wext;

    __shared__ float tile[16 * 129];
    #pragma unroll
    for (int it = 0; it < 8; ++it) {
        int idx = it * 256 + tid;
        int rr = idx >> 7, c = idx & 127;
        float v = (i < 128) ? lde(Wt, (size_t)(n8 * 16 + rr) * 16384 + (size_t)i * 128 + c, bf)
                            : lde(Ws, (size_t)(n8 * 16 + rr) * 256 + (size_t)(i - 128) * 128 + c, bf);
        tile[rr * 129 + c] = v;
    }
    __syncthreads();
    f16* out = dst + (size_t)(i * 8 + n8) * 2048;
    #pragma unroll
    for (int it = 0; it < 8; ++it) {
        int o = it * 256 + tid;
        int t = o >> 9, ln = (o >> 3) & 63, e = o & 7;
        __builtin_nontemporal_store((f16)tile[(ln & 15) * 129 + t * 32 + ((ln >> 4) << 3) + e],
                                    &out[o]);
    }
}

// ---------------------------------------------------------------------------
// GEMM over A_ext = [kron(l,r) | l | r] vs W, split-K over kron rows i.
// Body = the proven R18 kernel (4-slot 64 KB LDS ring, global_load_lds,
// counted-vmcnt d=3 pipeline, per-stage barrier; 108 VGPR, zero spill).
// R23: FUSED split-K epilogue (replaces the epi_level launches). Wall
// accounting: kernel-sum ~115-130 us vs wall 260 us => ~100-145 us is the 11
// kernel transitions; R22's cooperative mega-kernel is not graph-capturable
// (container died twice), so fusion is done with device-scope atomics:
//   store partial -> __syncthreads (drains stores, vmcnt 0) -> tid0:
//   __threadfence (release) + atomicAdd(cnt[gid]) -> last-of-S block
//   __threadfence (acquire) -> sum_s + bias + tanh -> h_out, re-arm cnt=0.
// No dispatch-order/co-residency assumption (G16): pure counting. Reduction
// s-order identical to epi_level -> bit-identical output. Counters zeroed by
// prep_all each launch AND self-re-armed -> graph replay safe.
// Block mapping is s-major: b = s*ngroups + gid, gid = mb*2+nh. Since
// ngroups % 8 == 0 at every level, all S blocks of a group share b%8
// (same XCD -> partials reduce mostly from local L2), and b%2 == nh
// preserves the nh<->XCD-parity W-half pinning.
// launch_bounds(256,2): the proven regalloc setting (tighter caps spill).
// s==1 appends lin-l (i=128), s==2 lin-r (i=129). Partials f16 -> part[s][p][n].
// ---------------------------------------------------------------------------
template<int BI, bool FUSE>
__launch_bounds__(256, 2)
__global__ void gemm_kernel(const f16* __restrict__ hin, const int* __restrict__ ids,
                            const f16* __restrict__ Wf,
                            f16* __restrict__ part, int Mrows, int S,
                            unsigned* __restrict__ cnt, const float* __restrict__ bias,
                            f16* __restrict__ hout)
{
    __shared__ f16 Wb[4][8192];         // 64 KB: 4-slot ring of 16 KB chunks

    const int tid  = threadIdx.x;
    const int lane = tid & 63;
    const int wv   = tid >> 6;                     // 0..3
    const int b    = blockIdx.x;
    const int ngroups = Mrows >> 7;                // (Mrows/256) mtiles * 2 nh
    const int lg   = 31 - __builtin_clz(ngroups);  // ngroups is pow2
    const int s    = b >> lg;
    const int gid  = b & (ngroups - 1);
    const int mb   = gid >> 1;
    const int nh   = gid & 1;                      // b%2 == nh -> XCD-parity pin
    const int m0   = mb * 256;
    const int i0   = s * BI;
    const bool tail = (s == 1 || s == 2);
    const int itail = (s == 1) ? 128 : 129;

    const int mrow = lane & 15;
    const int q    = lane >> 4;
    const int wm   = wv * 64;

    // ---- r fragments (A-layout) for this wave's 64 rows ----
    f16x8 rf[4][4];
    int rowL[4];
    #pragma unroll
    for (int mt = 0; mt < 4; ++mt) {
        int p = m0 + wm + mt * 16 + mrow;
        int row = ids ? ids[2 * p + 1] : 2 * p + 1;
        rowL[mt] = ids ? ids[2 * p] : 2 * p;
        #pragma unroll
        for (int t = 0; t < 4; ++t)
            rf[mt][t] = *(const f16x8*)&hin[(size_t)row * DD + t * 32 + q * 8];
    }

    // ---- l-window: this lane's 4 rows, halves [i0, i0+BI) in registers ----
    f16 lw[4][BI];
    #pragma unroll
    for (int mt = 0; mt < 4; ++mt) {
        const f16* src = &hin[(size_t)rowL[mt] * DD + i0];
        if constexpr (BI == 8)      { *(f16x8*)&lw[mt][0] = *(const f16x8*)src; }
        else if constexpr (BI == 4) { *(unsigned long long*)&lw[mt][0] = *(const unsigned long long*)src; }
        else if constexpr (BI == 2) { *(unsigned int*)&lw[mt][0] = *(const unsigned int*)src; }
        else                        { lw[mt][0] = src[0]; }
    }

    // ---- async W staging: one (i, nh) 16 KB chunk -> ring slot ----
    // 16 j-subchunks split across 4 waves -> 4 global_load_lds per wave/stage
    auto stage = [&](int i, int slot) {
        const f16* g = Wf + (size_t)i * 16384 + nh * 8192;
        #pragma unroll
        for (int k = 0; k < 4; ++k) {
            int j = k * 4 + wv;                    // 0..15
            const f16* gg = g + (size_t)(j * 64 + lane) * 8;
            f16* l = &Wb[slot][(size_t)(j * 64) * 8];
            __builtin_amdgcn_global_load_lds(
                (const __attribute__((address_space(1))) unsigned int*)gg,
                (__attribute__((address_space(3))) unsigned int*)l, 16, 0, 0);
        }
    };

    // ---- prologue: fill pipeline 3 deep ----
    stage(i0, 0);
    stage(i0 + 1, 1);                              // BI >= 2 always
    if constexpr (BI >= 3) {
        stage(i0 + 2, 2);
        wait_vmcnt<8>();                           // stage 0 landed (own wave)
    } else {                                       // BI == 2: tail goes in prologue
        if (tail) stage(itail, 2);
        wait_vmcnt<4>();                           // stage 0 landed (own wave)
    }
    __builtin_amdgcn_s_barrier();                  // -> stage 0 landed, all waves

    f32x4 acc[4][4] = {};

#define TSTEP(T, SLOT, KRON, LBV)                                                       \
    {                                                                                   \
        f16x8 wc[4];                                                                    \
        _Pragma("unroll")                                                               \
        for (int nt = 0; nt < 4; ++nt)                                                  \
            wc[nt] = *(const f16x8*)&Wb[SLOT][nt * 2048 + (T) * 512 + lane * 8];        \
        _Pragma("unroll")                                                               \
        for (int mt = 0; mt < 4; ++mt) {                                                \
            f16x8 a = (KRON) ? (LBV[mt] * rf[mt][T]) : rf[mt][T];                       \
            _Pragma("unroll")                                                           \
            for (int nt = 0; nt < 4; ++nt)                                              \
                acc[mt][nt] = __builtin_amdgcn_mfma_f32_16x16x32_f16(a, wc[nt], acc[mt][nt], 0, 0, 0); \
        }                                                                               \
    }

    #pragma unroll
    for (int ii = 0; ii < BI; ++ii) {
        // prefetch 3 stages ahead into ring slot (ii+3)&3 (tail stage = BI)
        if constexpr (BI >= 3) {
            if (ii + 3 < BI)                stage(i0 + ii + 3, (ii + 3) & 3);
            else if (ii + 3 == BI && tail)  stage(itail, BI & 3);
        }
        // counted wait: guarantee own stage-(ii+1) loads landed; the barrier
        // below publishes that cross-wave for the next iteration's reads.
        if (ii <= BI - 4)       wait_vmcnt<8>();   // 2 stages in flight
        else if (ii == BI - 3)  wait_vmcnt<4>();   // 1 stage
        else                    wait_vmcnt<0>();   // last two iters: drain
        // broadcast l values for this i (static lw index)
        f16x8 lb[4];
        #pragma unroll
        for (int mt = 0; mt < 4; ++mt) {
            f16 v = lw[mt][ii];
            #pragma unroll
            for (int e = 0; e < 8; ++e) lb[mt][e] = v;
        }
        __builtin_amdgcn_s_setprio(1);
        TSTEP(0, ii & 3, true, lb); TSTEP(1, ii & 3, true, lb);
        TSTEP(2, ii & 3, true, lb); TSTEP(3, ii & 3, true, lb);
        __builtin_amdgcn_s_setprio(0);
        if (ii + 1 < BI || tail) __builtin_amdgcn_s_barrier();
    }

    if (tail) {
        constexpr int slot = (BI >= 3) ? (BI & 3) : 2;
        if (s == 1) {       // lin-l: overwrite rf with l-row A-frags
            #pragma unroll
            for (int mt = 0; mt < 4; ++mt)
                #pragma unroll
                for (int t = 0; t < 4; ++t)
                    rf[mt][t] = *(const f16x8*)&hin[(size_t)rowL[mt] * DD + t * 32 + q * 8];
        }
        f16x8 dummy[4];
        __builtin_amdgcn_s_setprio(1);
        TSTEP(0, slot, false, dummy); TSTEP(1, slot, false, dummy);
        TSTEP(2, slot, false, dummy); TSTEP(3, slot, false, dummy);
        __builtin_amdgcn_s_setprio(0);
    }
#undef TSTEP

    // ---- store f16 partial tile: C/D layout col=lane&15, row=q*4+reg ----
    f16* pb = part + ((size_t)s * Mrows + m0) * DD + nh * 64;
    #pragma unroll
    for (int mt = 0; mt < 4; ++mt)
        #pragma unroll
        for (int nt = 0; nt < 4; ++nt) {
            int colg = nt * 16 + mrow;
            #pragma unroll
            for (int rr = 0; rr < 4; ++rr) {
                int rowl = wm + mt * 16 + q * 4 + rr;
                pb[(size_t)rowl * DD + colg] = (f16)acc[mt][nt][rr];
            }
        }

    // ---- fused split-K epilogue: last-of-S block reduces this (mb,nh) ----
    if constexpr (FUSE) {
        __syncthreads();                 // Wb dead; all waves' stores vmcnt-drained
        volatile int* flagp = (volatile int*)&Wb[0][0];
        if (tid == 0) {
            __threadfence();             // release: publish partials device-wide
            unsigned old = atomicAdd(&cnt[gid], 1u);
            *flagp = (old == (unsigned)(S - 1)) ? 1 : 0;
        }
        __syncthreads();
        if (*flagp == 0) return;
        __threadfence();                 // acquire: drop stale cached lines
        const size_t stride = (size_t)Mrows * DD;
        const f16* pr = part + (size_t)m0 * DD + nh * 64;
        #pragma unroll
        for (int it = 0; it < 8; ++it) {
            int vi   = it * 256 + tid;   // 2048 vecs = 256 rows x 8 vecs
            int rowl = vi >> 3, cv = vi & 7;
            size_t off = (size_t)rowl * DD + cv * 8;
            float sum[8] = {};
            for (int s2 = 0; s2 < S; ++s2) {   // same s-order as epi_level
                f16x8 v = *(const f16x8*)&pr[(size_t)s2 * stride + off];
                #pragma unroll
                for (int e = 0; e < 8; ++e) sum[e] += (float)v[e];
            }
            int ncol = nh * 64 + cv * 8;
            f16x8 o;
            #pragma unroll
            for (int e = 0; e < 8; ++e) o[e] = (f16)tanhf(sum[e] + bias[ncol + e]);
            *(f16x8*)&hout[(size_t)(m0 + rowl) * DD + ncol] = o;
        }
        if (tid == 0) atomicExch(&cnt[gid], 0u);   // re-arm for graph replay
    }
}

// ---------------------------------------------------------------------------
// final epilogue: leaky_relu(sum_s part + bias) @ Wsm^T + bsm -> log_softmax
// ---------------------------------------------------------------------------
__global__ void fin_epi(const f16* __restrict__ part, const float* __restrict__ bias,
                        const float* __restrict__ Wsm_f, const float* __restrict__ bsm_f,
                        const unsigned short* __restrict__ wv_raw, void* __restrict__ outp, int S)
{
    int lane = threadIdx.x & 63;
    int wv = threadIdx.x >> 6;
    int p = blockIdx.x * 4 + wv;              // 0..511
    size_t stride = (size_t)512 * DD;
    const f16* base = part + (size_t)p * DD;
    float a0 = 0.f, a1 = 0.f;
    for (int s2 = 0; s2 < S; ++s2) {
        a0 += (float)base[(size_t)s2 * stride + lane];
        a1 += (float)base[(size_t)s2 * stride + 64 + lane];
    }
    a0 += bias[lane];      a1 += bias[64 + lane];
    a0 = (a0 > 0.f) ? a0 : 0.01f * a0;
    a1 = (a1 > 0.f) ? a1 : 0.01f * a1;
    float lg[NRELS];
    #pragma unroll
    for (int r = 0; r < NRELS; ++r) {
        float pr = a0 * Wsm_f[r * DD + lane] + a1 * Wsm_f[r * DD + 64 + lane];
        #pragma unroll
        for (int d = 1; d < 64; d <<= 1) pr += __shfl_xor(pr, d, 64);
        lg[r] = pr + bsm_f[r];
    }
    float mx = lg[0];
    #pragma unroll
    for (int r = 1; r < NRELS; ++r) mx = fmaxf(mx, lg[r]);
    float se = 0.f;
    #pragma unroll
    for (int r = 0; r < NRELS; ++r) se += expf(lg[r] - mx);
    float lse = logf(se) + mx;
    if (lane < NRELS) {
        float v = lg[lane] - lse;
        if (detect_bf(wv_raw)) ((__hip_bfloat16*)outp)[p * NRELS + lane] = __float2bfloat16(v);
        else                   ((float*)outp)[p * NRELS + lane] = v;
    }
}

// ---------------------------------------------------------------------------
extern "C" void kernel_launch(void* const* d_in, const int* in_sizes, int n_in,
                              void* d_out, int out_size, void* d_ws, size_t ws_size,
                              hipStream_t stream)
{
    const int* ids = (const int*)d_in[0];

    char* ws = (char*)d_ws;
    f16*   part     = (f16*)ws;                                      // 32 MiB region (f16 partials)
    f16*   h1       = (f16*)(ws + ((size_t)32 << 20));               // 2 MiB
    f16*   h2       = (f16*)(ws + ((size_t)34 << 20));               // 1 MiB
    f16*   h3       = (f16*)(ws + ((size_t)35 << 20));               // 0.5 MiB
    f16*   h4       = (f16*)(ws + ((size_t)35 << 20) + (512 << 10)); // 0.25 MiB
    f16*   WvT      = (f16*)(ws + ((size_t)36 << 20));               // 0.5 MiB
    f16*   Wext     = (f16*)(ws + ((size_t)36 << 20) + (512 << 10)); // 4.0625 MiB
    f16*   Wfin     = Wext + (size_t)NWF;                            // 4.0625 MiB
    float* bias_lvl = (float*)(Wfin + (size_t)NWF);
    float* bias_fin = bias_lvl + 128;
    float* Wsm_f    = bias_fin + 128;
    float* bsm_f    = Wsm_f + NRELS * DD;
    unsigned* cnt   = (unsigned*)(bsm_f + NRELS);    // 128 split-K counters
    // cnt layout: level1 @0 (64), level2 @64 (32), level3 @96 (16), level4 @112 (8)

    if (ws_size < ((size_t)48 << 20)) return;

    prep_all<<<2145, 256, 0, stream>>>(d_in[1], d_in[2], d_in[3], d_in[4], d_in[5], d_in[6],
                                       d_in[7], d_in[8], d_in[9], d_in[10], d_in[11], d_in[12],
                                       WvT, Wext, Wfin, bias_lvl, bias_fin, Wsm_f, bsm_f, cnt);

    // R23: 7 launches (was 11). Fused gemm+epi for levels 1-4; s-major grids.
    // level 1 (fused embed-gather): M=8192, 64 groups x S=16 -> 1024
    gemm_kernel<8, true ><<<1024, 256, 0, stream>>>(WvT, ids, Wext, part, 8192, 16,
                                                    cnt +   0, bias_lvl, h1);
    // level 2: M=4096, 32 groups x S=16 -> 512
    gemm_kernel<8, true ><<<512, 256, 0, stream>>>(h1, nullptr, Wext, part, 4096, 16,
                                                   cnt +  64, bias_lvl, h2);
    // level 3: M=2048, 16 groups x S=32 -> 512
    gemm_kernel<4, true ><<<512, 256, 0, stream>>>(h2, nullptr, Wext, part, 2048, 32,
                                                   cnt +  96, bias_lvl, h3);
    // level 4: M=1024, 8 groups x S=32 -> 256
    gemm_kernel<4, true ><<<256, 256, 0, stream>>>(h3, nullptr, Wext, part, 1024, 32,
                                                   cnt + 112, bias_lvl, h4);
    // final level: M=512, 4 groups x S=64 -> 256 (no fusion; fin reduces)
    gemm_kernel<2, false><<<256, 256, 0, stream>>>(h4, nullptr, Wfin, part, 512, 64,
                                                   nullptr, nullptr, nullptr);
    fin_epi<<<128, 256, 0, stream>>>(part, bias_fin, Wsm_f, bsm_f,
                                     (const unsigned short*)d_in[1], d_out, 64);
}

// Round 9
// 498.539 us; speedup vs baseline: 1.0123x; 1.0123x over previous
//
#include <hip/hip_runtime.h>
#include <hip/hip_bf16.h>
#include <hip/hip_fp16.h>

#define DD    128
#define VOCAB 2048
#define NRELS 7
#define NWF   (130 * 16384)   // W frag-layout elements: 128 kron + l + r chunks

typedef _Float16 f16;
typedef __attribute__((ext_vector_type(8))) _Float16 f16x8;
typedef __attribute__((ext_vector_type(4))) _Float16 f16x4;
typedef __attribute__((ext_vector_type(4))) float    f32x4;

// flexible-dtype load: bf==1 -> bf16 storage, bf==0 -> f32 storage
__device__ __forceinline__ float lde(const void* p, size_t i, int bf) {
    if (bf) return (float)((const __hip_bfloat16*)p)[i];
    return ((const float*)p)[i];
}

// detect storage dtype by exponent-field sanity of Wv's first 64 uint16s
__device__ __forceinline__ int detect_bf(const unsigned short* wv) {
    int sane = 0;
    #pragma unroll
    for (int i = 0; i < 64; ++i) {
        unsigned e = (wv[i] >> 7) & 0xFFu;
        sane += (e >= 90u && e <= 160u) ? 1 : 0;
    }
    return sane == 64;
}

// counted vmcnt wait (T4). N is a compile-time literal.
template<int N>
__device__ __forceinline__ void wait_vmcnt() {
    asm volatile("s_waitcnt vmcnt(%0)" :: "n"(N) : "memory");
}

// ---------------------------------------------------------------------------
// prep_all: WvT transpose, W frag-major repack (NT stores: write-once data),
// biases, zero split-K counters (graph-replay belt; reducers also re-arm).
// Frag layout: Wf[((i*8+n8)*4+t)*512 + ln*8 + e] =
//              W[n8*16+(ln&15)][i*128 + t*32 + (ln>>4)*8 + e]
// ---------------------------------------------------------------------------
__global__ void prep_all(const void* Wv, const void* bv,
                         const void* Wcps, const void* bcps,
                         const void* Wcpst, const void* bcpst,
                         const void* Wcpr, const void* bcpr,
                         const void* Wcprt, const void* bcprt,
                         const void* Wsm, const void* bsm,
                         f16* __restrict__ WvT, f16* __restrict__ Wext, f16* __restrict__ Wfin,
                         float* __restrict__ bias_lvl, float* __restrict__ bias_fin,
                         float* __restrict__ Wsm_f, float* __restrict__ bsm_f,
                         unsigned* __restrict__ cnt)
{
    const int bf = detect_bf((const unsigned short*)Wv);
    const int b = blockIdx.x;
    const int tid = threadIdx.x;

    if (b < 64) {                     // ---- WvT transpose ----
        __shared__ float tile[64][65];
        int vt = b >> 1, dt = b & 1;
        int tx = tid & 63, ty = tid >> 6;
        for (int yy = ty; yy < 64; yy += 4)
            tile[yy][tx] = lde(Wv, (size_t)(dt * 64 + yy) * VOCAB + vt * 64 + tx, bf);
        __syncthreads();
        for (int yy = ty; yy < 64; yy += 4) {
            int v = vt * 64 + yy, d = dt * 64 + tx;
            __builtin_nontemporal_store((f16)(tile[tx][yy] + lde(bv, d, bf)),
                                        &WvT[(size_t)v * DD + d]);
        }
        return;
    }
    if (b >= 2144) {                  // ---- biases + softmax weights + counters ----
        if (tid < 128) {
            bias_lvl[tid] = lde(bcps, tid, bf) + lde(bcpst, tid, bf);
            cnt[tid] = 0u;
        } else if (tid < 256) {
            bias_fin[tid - 128] = lde(bcpr, tid - 128, bf) + lde(bcprt, tid - 128, bf);
        }
        for (int o = tid; o < NRELS * DD; o += 256) Wsm_f[o] = lde(Wsm, o, bf);
        if (tid < NRELS) bsm_f[tid] = lde(bsm, tid, bf);
        return;
    }
    // ---- W frag repack ----
    const int bb    = b - 64;
    const int which = bb / 1040;      // 0: ext, 1: fin
    const int rem   = bb - which * 1040;
    const int i     = rem >> 3;       // 0..129
    const int n8    = rem & 7;
    const void* Wt = which ? (const void*)Wcprt : (const void*)Wcpst;
    const void* Ws = which ? (const void*)Wcpr  : (const void*)Wcps;
    f16* dst = which ? Wfin : Wext;

    __shared__ float tile[16 * 129];
    #pragma unroll
    for (int it = 0; it < 8; ++it) {
        int idx = it * 256 + tid;
        int rr = idx >> 7, c = idx & 127;
        float v = (i < 128) ? lde(Wt, (size_t)(n8 * 16 + rr) * 16384 + (size_t)i * 128 + c, bf)
                            : lde(Ws, (size_t)(n8 * 16 + rr) * 256 + (size_t)(i - 128) * 128 + c, bf);
        tile[rr * 129 + c] = v;
    }
    __syncthreads();
    f16* out = dst + (size_t)(i * 8 + n8) * 2048;
    #pragma unroll
    for (int it = 0; it < 8; ++it) {
        int o = it * 256 + tid;
        int t = o >> 9, ln = (o >> 3) & 63, e = o & 7;
        __builtin_nontemporal_store((f16)tile[(ln & 15) * 129 + t * 32 + ((ln >> 4) << 3) + e],
                                    &out[o]);
    }
}

// ---------------------------------------------------------------------------
// GEMM over A_ext = [kron(l,r) | l | r] vs W, split-K over kron rows i.
// Body = the byte-exact R18 kernel (4-slot 64 KB LDS ring, global_load_lds,
// counted-vmcnt d=3 pipeline, per-stage barrier; 108 VGPR; original R13
// block mapping nh=(b>>2)&1, r=((b>>3)<<2)|(b&3) — R23's s-major remap
// dropped).
// R24 fusion: split-K epilogue fused WITHOUT cache-maintenance fences.
// R23's __threadfence() emitted buffer_wbl2/buffer_inv on gfx950 (per-XCD
// L2s non-coherent -> agent fences flush L2), which evicted the L2-resident
// W tiles for every co-resident block: FETCH 4.5->26.8 MB, MfmaUtil 28->11%,
// gemm1 2.6x slower. Fix: cross-block data NEVER touches L2 —
//   partial stores:  __hip_atomic_store  relaxed/agent  (global_store sc1,
//                    write-through to the coherent point, no L2 dirty lines)
//   completion:      __syncthreads (drains each wave's vmcnt -> sc1 stores
//                    globally visible) + tid0 relaxed/agent fetch_add
//   last-of-S block: relaxed/agent 8B loads (sc1, reads L3 directly; no
//                    buffer_inv needed since L2 was never populated)
// Zero wbl2/inv instructions; W stays warm in L2. No dispatch-order or
// co-residency assumption (G16): pure counting. Reduction s-order identical
// to epi_level -> bit-identical output. Counters zeroed by prep_all AND
// re-armed by the reducer -> graph-replay safe.
// launch_bounds(256,2): the proven regalloc setting (tighter caps spill).
// s==1 appends lin-l (i=128), s==2 lin-r (i=129). Partials -> part[s][p][n].
// ---------------------------------------------------------------------------
template<int BI, bool FUSE>
__launch_bounds__(256, 2)
__global__ void gemm_kernel(const f16* __restrict__ hin, const int* __restrict__ ids,
                            const f16* __restrict__ Wf,
                            f16* __restrict__ part, int Mrows, int S,
                            unsigned* __restrict__ cnt, const float* __restrict__ bias,
                            f16* __restrict__ hout)
{
    __shared__ f16 Wb[4][8192];         // 64 KB: 4-slot ring of 16 KB chunks

    const int tid  = threadIdx.x;
    const int lane = tid & 63;
    const int wv   = tid >> 6;                     // 0..3
    const int b    = blockIdx.x;
    const int nh   = (b >> 2) & 1;                 // XCD-half -> n-half
    const int r    = ((b >> 3) << 2) | (b & 3);
    const int mb   = r / S;
    const int s    = r - mb * S;
    const int m0   = mb * 256;
    const int i0   = s * BI;
    const bool tail = (s == 1 || s == 2);
    const int itail = (s == 1) ? 128 : 129;

    const int mrow = lane & 15;
    const int q    = lane >> 4;
    const int wm   = wv * 64;

    // ---- r fragments (A-layout) for this wave's 64 rows ----
    f16x8 rf[4][4];
    int rowL[4];
    #pragma unroll
    for (int mt = 0; mt < 4; ++mt) {
        int p = m0 + wm + mt * 16 + mrow;
        int row = ids ? ids[2 * p + 1] : 2 * p + 1;
        rowL[mt] = ids ? ids[2 * p] : 2 * p;
        #pragma unroll
        for (int t = 0; t < 4; ++t)
            rf[mt][t] = *(const f16x8*)&hin[(size_t)row * DD + t * 32 + q * 8];
    }

    // ---- l-window: this lane's 4 rows, halves [i0, i0+BI) in registers ----
    f16 lw[4][BI];
    #pragma unroll
    for (int mt = 0; mt < 4; ++mt) {
        const f16* src = &hin[(size_t)rowL[mt] * DD + i0];
        if constexpr (BI == 8)      { *(f16x8*)&lw[mt][0] = *(const f16x8*)src; }
        else if constexpr (BI == 4) { *(unsigned long long*)&lw[mt][0] = *(const unsigned long long*)src; }
        else if constexpr (BI == 2) { *(unsigned int*)&lw[mt][0] = *(const unsigned int*)src; }
        else                        { lw[mt][0] = src[0]; }
    }

    // ---- async W staging: one (i, nh) 16 KB chunk -> ring slot ----
    // 16 j-subchunks split across 4 waves -> 4 global_load_lds per wave/stage
    auto stage = [&](int i, int slot) {
        const f16* g = Wf + (size_t)i * 16384 + nh * 8192;
        #pragma unroll
        for (int k = 0; k < 4; ++k) {
            int j = k * 4 + wv;                    // 0..15
            const f16* gg = g + (size_t)(j * 64 + lane) * 8;
            f16* l = &Wb[slot][(size_t)(j * 64) * 8];
            __builtin_amdgcn_global_load_lds(
                (const __attribute__((address_space(1))) unsigned int*)gg,
                (__attribute__((address_space(3))) unsigned int*)l, 16, 0, 0);
        }
    };

    // ---- prologue: fill pipeline 3 deep ----
    stage(i0, 0);
    stage(i0 + 1, 1);                              // BI >= 2 always
    if constexpr (BI >= 3) {
        stage(i0 + 2, 2);
        wait_vmcnt<8>();                           // stage 0 landed (own wave)
    } else {                                       // BI == 2: tail goes in prologue
        if (tail) stage(itail, 2);
        wait_vmcnt<4>();                           // stage 0 landed (own wave)
    }
    __builtin_amdgcn_s_barrier();                  // -> stage 0 landed, all waves

    f32x4 acc[4][4] = {};

#define TSTEP(T, SLOT, KRON, LBV)                                                       \
    {                                                                                   \
        f16x8 wc[4];                                                                    \
        _Pragma("unroll")                                                               \
        for (int nt = 0; nt < 4; ++nt)                                                  \
            wc[nt] = *(const f16x8*)&Wb[SLOT][nt * 2048 + (T) * 512 + lane * 8];        \
        _Pragma("unroll")                                                               \
        for (int mt = 0; mt < 4; ++mt) {                                                \
            f16x8 a = (KRON) ? (LBV[mt] * rf[mt][T]) : rf[mt][T];                       \
            _Pragma("unroll")                                                           \
            for (int nt = 0; nt < 4; ++nt)                                              \
                acc[mt][nt] = __builtin_amdgcn_mfma_f32_16x16x32_f16(a, wc[nt], acc[mt][nt], 0, 0, 0); \
        }                                                                               \
    }

    #pragma unroll
    for (int ii = 0; ii < BI; ++ii) {
        // prefetch 3 stages ahead into ring slot (ii+3)&3 (tail stage = BI)
        if constexpr (BI >= 3) {
            if (ii + 3 < BI)                stage(i0 + ii + 3, (ii + 3) & 3);
            else if (ii + 3 == BI && tail)  stage(itail, BI & 3);
        }
        // counted wait: guarantee own stage-(ii+1) loads landed; the barrier
        // below publishes that cross-wave for the next iteration's reads.
        if (ii <= BI - 4)       wait_vmcnt<8>();   // 2 stages in flight
        else if (ii == BI - 3)  wait_vmcnt<4>();   // 1 stage
        else                    wait_vmcnt<0>();   // last two iters: drain
        // broadcast l values for this i (static lw index)
        f16x8 lb[4];
        #pragma unroll
        for (int mt = 0; mt < 4; ++mt) {
            f16 v = lw[mt][ii];
            #pragma unroll
            for (int e = 0; e < 8; ++e) lb[mt][e] = v;
        }
        __builtin_amdgcn_s_setprio(1);
        TSTEP(0, ii & 3, true, lb); TSTEP(1, ii & 3, true, lb);
        TSTEP(2, ii & 3, true, lb); TSTEP(3, ii & 3, true, lb);
        __builtin_amdgcn_s_setprio(0);
        if (ii + 1 < BI || tail) __builtin_amdgcn_s_barrier();
    }

    if (tail) {
        constexpr int slot = (BI >= 3) ? (BI & 3) : 2;
        if (s == 1) {       // lin-l: overwrite rf with l-row A-frags
            #pragma unroll
            for (int mt = 0; mt < 4; ++mt)
                #pragma unroll
                for (int t = 0; t < 4; ++t)
                    rf[mt][t] = *(const f16x8*)&hin[(size_t)rowL[mt] * DD + t * 32 + q * 8];
        }
        f16x8 dummy[4];
        __builtin_amdgcn_s_setprio(1);
        TSTEP(0, slot, false, dummy); TSTEP(1, slot, false, dummy);
        TSTEP(2, slot, false, dummy); TSTEP(3, slot, false, dummy);
        __builtin_amdgcn_s_setprio(0);
    }
#undef TSTEP

    // ---- store f16 partial tile: C/D layout col=lane&15, row=q*4+reg ----
    // FUSE: sc1 (agent-scope relaxed) stores — bypass L2, land at the
    // coherent point; no dirty L2 lines -> no fence needed later.
    f16* pb = part + ((size_t)s * Mrows + m0) * DD + nh * 64;
    #pragma unroll
    for (int mt = 0; mt < 4; ++mt)
        #pragma unroll
        for (int nt = 0; nt < 4; ++nt) {
            int colg = nt * 16 + mrow;
            #pragma unroll
            for (int rr = 0; rr < 4; ++rr) {
                int rowl = wm + mt * 16 + q * 4 + rr;
                f16 v = (f16)acc[mt][nt][rr];
                if constexpr (FUSE)
                    __hip_atomic_store((unsigned short*)&pb[(size_t)rowl * DD + colg],
                                       __builtin_bit_cast(unsigned short, v),
                                       __ATOMIC_RELAXED, __HIP_MEMORY_SCOPE_AGENT);
                else
                    pb[(size_t)rowl * DD + colg] = v;
            }
        }

    // ---- fused split-K epilogue: last-of-S block reduces this (mb,nh) ----
    if constexpr (FUSE) {
        // __syncthreads drains each wave's vmcnt before s_barrier -> all of
        // this block's sc1 stores are globally visible once we pass it.
        __syncthreads();
        int* flagp = (int*)&Wb[0][0];              // ring is dead now
        if (tid == 0) {
            unsigned old = __hip_atomic_fetch_add(&cnt[mb * 2 + nh], 1u,
                                                  __ATOMIC_RELAXED, __HIP_MEMORY_SCOPE_AGENT);
            *flagp = (old == (unsigned)(S - 1)) ? 1 : 0;
        }
        __syncthreads();
        if (*flagp == 0) return;
        // we are the last block of the group: all S blocks' sc1 stores are at
        // the coherent point; read them with sc1 loads (never in our L2).
        const size_t stride = (size_t)Mrows * DD;
        const f16* pr = part + (size_t)m0 * DD + nh * 64;
        #pragma unroll
        for (int it = 0; it < 8; ++it) {
            int vi   = it * 256 + tid;   // 2048 vecs = 256 rows x 8 vecs(8 f16)
            int rowl = vi >> 3, cv = vi & 7;
            size_t off = (size_t)rowl * DD + cv * 8;
            float sum[8] = {};
            for (int s2 = 0; s2 < S; ++s2) {       // same s-order as epi_level
                const unsigned long long* pp =
                    (const unsigned long long*)&pr[(size_t)s2 * stride + off];
                unsigned long long u0 = __hip_atomic_load(pp,     __ATOMIC_RELAXED, __HIP_MEMORY_SCOPE_AGENT);
                unsigned long long u1 = __hip_atomic_load(pp + 1, __ATOMIC_RELAXED, __HIP_MEMORY_SCOPE_AGENT);
                f16x4 a = __builtin_bit_cast(f16x4, u0);
                f16x4 c = __builtin_bit_cast(f16x4, u1);
                #pragma unroll
                for (int e = 0; e < 4; ++e) { sum[e] += (float)a[e]; sum[4 + e] += (float)c[e]; }
            }
            int ncol = nh * 64 + cv * 8;
            f16x8 o;
            #pragma unroll
            for (int e = 0; e < 8; ++e) o[e] = (f16)tanhf(sum[e] + bias[ncol + e]);
            *(f16x8*)&hout[(size_t)(m0 + rowl) * DD + ncol] = o;   // normal store:
            // consumed by the NEXT KERNEL -> kernel boundary provides coherence
        }
        if (tid == 0)
            __hip_atomic_store(&cnt[mb * 2 + nh], 0u,
                               __ATOMIC_RELAXED, __HIP_MEMORY_SCOPE_AGENT);  // re-arm
    }
}

// ---------------------------------------------------------------------------
// final epilogue: leaky_relu(sum_s part + bias) @ Wsm^T + bsm -> log_softmax
// ---------------------------------------------------------------------------
__global__ void fin_epi(const f16* __restrict__ part, const float* __restrict__ bias,
                        const float* __restrict__ Wsm_f, const float* __restrict__ bsm_f,
                        const unsigned short* __restrict__ wv_raw, void* __restrict__ outp, int S)
{
    int lane = threadIdx.x & 63;
    int wv = threadIdx.x >> 6;
    int p = blockIdx.x * 4 + wv;              // 0..511
    size_t stride = (size_t)512 * DD;
    const f16* base = part + (size_t)p * DD;
    float a0 = 0.f, a1 = 0.f;
    for (int s2 = 0; s2 < S; ++s2) {
        a0 += (float)base[(size_t)s2 * stride + lane];
        a1 += (float)base[(size_t)s2 * stride + 64 + lane];
    }
    a0 += bias[lane];      a1 += bias[64 + lane];
    a0 = (a0 > 0.f) ? a0 : 0.01f * a0;
    a1 = (a1 > 0.f) ? a1 : 0.01f * a1;
    float lg[NRELS];
    #pragma unroll
    for (int r = 0; r < NRELS; ++r) {
        float pr = a0 * Wsm_f[r * DD + lane] + a1 * Wsm_f[r * DD + 64 + lane];
        #pragma unroll
        for (int d = 1; d < 64; d <<= 1) pr += __shfl_xor(pr, d, 64);
        lg[r] = pr + bsm_f[r];
    }
    float mx = lg[0];
    #pragma unroll
    for (int r = 1; r < NRELS; ++r) mx = fmaxf(mx, lg[r]);
    float se = 0.f;
    #pragma unroll
    for (int r = 0; r < NRELS; ++r) se += expf(lg[r] - mx);
    float lse = logf(se) + mx;
    if (lane < NRELS) {
        float v = lg[lane] - lse;
        if (detect_bf(wv_raw)) ((__hip_bfloat16*)outp)[p * NRELS + lane] = __float2bfloat16(v);
        else                   ((float*)outp)[p * NRELS + lane] = v;
    }
}

// ---------------------------------------------------------------------------
extern "C" void kernel_launch(void* const* d_in, const int* in_sizes, int n_in,
                              void* d_out, int out_size, void* d_ws, size_t ws_size,
                              hipStream_t stream)
{
    const int* ids = (const int*)d_in[0];

    char* ws = (char*)d_ws;
    f16*   part     = (f16*)ws;                                      // 32 MiB region (f16 partials)
    f16*   h1       = (f16*)(ws + ((size_t)32 << 20));               // 2 MiB
    f16*   h2       = (f16*)(ws + ((size_t)34 << 20));               // 1 MiB
    f16*   h3       = (f16*)(ws + ((size_t)35 << 20));               // 0.5 MiB
    f16*   h4       = (f16*)(ws + ((size_t)35 << 20) + (512 << 10)); // 0.25 MiB
    f16*   WvT      = (f16*)(ws + ((size_t)36 << 20));               // 0.5 MiB
    f16*   Wext     = (f16*)(ws + ((size_t)36 << 20) + (512 << 10)); // 4.0625 MiB
    f16*   Wfin     = Wext + (size_t)NWF;                            // 4.0625 MiB
    float* bias_lvl = (float*)(Wfin + (size_t)NWF);
    float* bias_fin = bias_lvl + 128;
    float* Wsm_f    = bias_fin + 128;
    float* bsm_f    = Wsm_f + NRELS * DD;
    unsigned* cnt   = (unsigned*)(bsm_f + NRELS);    // 128 split-K counters
    // cnt layout: level1 @0 (64), level2 @64 (32), level3 @96 (16), level4 @112 (8)

    if (ws_size < ((size_t)48 << 20)) return;

    prep_all<<<2145, 256, 0, stream>>>(d_in[1], d_in[2], d_in[3], d_in[4], d_in[5], d_in[6],
                                       d_in[7], d_in[8], d_in[9], d_in[10], d_in[11], d_in[12],
                                       WvT, Wext, Wfin, bias_lvl, bias_fin, Wsm_f, bsm_f, cnt);

    // R24: 7 launches (was 11). R13 grid schedule + R18 counted-vmcnt ring
    // K-loop + sc1-fused split-K epilogues (levels 1-4).
    // level 1 (fused embed-gather): M=8192, 32 mtiles(256) x S=16 x 2 nh -> 1024
    gemm_kernel<8, true ><<<1024, 256, 0, stream>>>(WvT, ids, Wext, part, 8192, 16,
                                                    cnt +   0, bias_lvl, h1);
    // level 2: M=4096, 16 mtiles x S=16 x 2 -> 512
    gemm_kernel<8, true ><<<512, 256, 0, stream>>>(h1, nullptr, Wext, part, 4096, 16,
                                                   cnt +  64, bias_lvl, h2);
    // level 3: M=2048, 8 mtiles x S=32 x 2 -> 512
    gemm_kernel<4, true ><<<512, 256, 0, stream>>>(h2, nullptr, Wext, part, 2048, 32,
                                                   cnt +  96, bias_lvl, h3);
    // level 4: M=1024, 4 mtiles x S=32 x 2 -> 256
    gemm_kernel<4, true ><<<256, 256, 0, stream>>>(h3, nullptr, Wext, part, 1024, 32,
                                                   cnt + 112, bias_lvl, h4);
    // final: M=512, 2 mtiles x S=64 x 2 -> 256 (unfused; fin reduces across nh)
    gemm_kernel<2, false><<<256, 256, 0, stream>>>(h4, nullptr, Wfin, part, 512, 64,
                                                   nullptr, nullptr, nullptr);
    fin_epi<<<128, 256, 0, stream>>>(part, bias_fin, Wsm_f, bsm_f,
                                     (const unsigned short*)d_in[1], d_out, 64);
}

// Round 10
// 309.585 us; speedup vs baseline: 1.6302x; 1.6103x over previous
//
#include <hip/hip_runtime.h>
#include <hip/hip_bf16.h>
#include <hip/hip_fp16.h>

#define DD    128
#define VOCAB 2048
#define NRELS 7
#define NWF   (130 * 16384)   // W frag-layout elements: 128 kron + l + r chunks

typedef _Float16 f16;
typedef __attribute__((ext_vector_type(8))) _Float16 f16x8;
typedef __attribute__((ext_vector_type(4))) float    f32x4;

// flexible-dtype load: bf==1 -> bf16 storage, bf==0 -> f32 storage
__device__ __forceinline__ float lde(const void* p, size_t i, int bf) {
    if (bf) return (float)((const __hip_bfloat16*)p)[i];
    return ((const float*)p)[i];
}

// detect storage dtype by exponent-field sanity of Wv's first 64 uint16s
__device__ __forceinline__ int detect_bf(const unsigned short* wv) {
    int sane = 0;
    #pragma unroll
    for (int i = 0; i < 64; ++i) {
        unsigned e = (wv[i] >> 7) & 0xFFu;
        sane += (e >= 90u && e <= 160u) ? 1 : 0;
    }
    return sane == 64;
}

// counted vmcnt wait. N is a compile-time literal.
template<int N>
__device__ __forceinline__ void wait_vmcnt() {
    asm volatile("s_waitcnt vmcnt(%0)" :: "n"(N) : "memory");
}

// ---------------------------------------------------------------------------
// prep_all: WvT transpose, W frag-major repack (NT stores: write-once data),
// biases. Frag layout: Wf[((i*8+n8)*4+t)*512 + ln*8 + e] =
//                      W[n8*16+(ln&15)][i*128 + t*32 + (ln>>4)*8 + e]
// ---------------------------------------------------------------------------
__global__ void prep_all(const void* Wv, const void* bv,
                         const void* Wcps, const void* bcps,
                         const void* Wcpst, const void* bcpst,
                         const void* Wcpr, const void* bcpr,
                         const void* Wcprt, const void* bcprt,
                         const void* Wsm, const void* bsm,
                         f16* __restrict__ WvT, f16* __restrict__ Wext, f16* __restrict__ Wfin,
                         float* __restrict__ bias_lvl, float* __restrict__ bias_fin,
                         float* __restrict__ Wsm_f, float* __restrict__ bsm_f)
{
    const int bf = detect_bf((const unsigned short*)Wv);
    const int b = blockIdx.x;
    const int tid = threadIdx.x;

    if (b < 64) {                     // ---- WvT transpose ----
        __shared__ float tile[64][65];
        int vt = b >> 1, dt = b & 1;
        int tx = tid & 63, ty = tid >> 6;
        for (int yy = ty; yy < 64; yy += 4)
            tile[yy][tx] = lde(Wv, (size_t)(dt * 64 + yy) * VOCAB + vt * 64 + tx, bf);
        __syncthreads();
        for (int yy = ty; yy < 64; yy += 4) {
            int v = vt * 64 + yy, d = dt * 64 + tx;
            __builtin_nontemporal_store((f16)(tile[tx][yy] + lde(bv, d, bf)),
                                        &WvT[(size_t)v * DD + d]);
        }
        return;
    }
    if (b >= 2144) {                  // ---- biases + softmax weights ----
        if (tid < 128)      bias_lvl[tid] = lde(bcps, tid, bf) + lde(bcpst, tid, bf);
        else if (tid < 256) bias_fin[tid - 128] = lde(bcpr, tid - 128, bf) + lde(bcprt, tid - 128, bf);
        for (int o = tid; o < NRELS * DD; o += 256) Wsm_f[o] = lde(Wsm, o, bf);
        if (tid < NRELS) bsm_f[tid] = lde(bsm, tid, bf);
        return;
    }
    // ---- W frag repack ----
    const int bb    = b - 64;
    const int which = bb / 1040;      // 0: ext, 1: fin
    const int rem   = bb - which * 1040;
    const int i     = rem >> 3;       // 0..129
    const int n8    = rem & 7;
    const void* Wt = which ? (const void*)Wcprt : (const void*)Wcpst;
    const void* Ws = which ? (const void*)Wcpr  : (const void*)Wcps;
    f16* dst = which ? Wfin : Wext;

    __shared__ float tile[16 * 129];
    #pragma unroll
    for (int it = 0; it < 8; ++it) {
        int idx = it * 256 + tid;
        int rr = idx >> 7, c = idx & 127;
        float v = (i < 128) ? lde(Wt, (size_t)(n8 * 16 + rr) * 16384 + (size_t)i * 128 + c, bf)
                            : lde(Ws, (size_t)(n8 * 16 + rr) * 256 + (size_t)(i - 128) * 128 + c, bf);
        tile[rr * 129 + c] = v;
    }
    __syncthreads();
    f16* out = dst + (size_t)(i * 8 + n8) * 2048;
    #pragma unroll
    for (int it = 0; it < 8; ++it) {
        int o = it * 256 + tid;
        int t = o >> 9, ln = (o >> 3) & 63, e = o & 7;
        __builtin_nontemporal_store((f16)tile[(ln & 15) * 129 + t * 32 + ((ln >> 4) << 3) + e],
                                    &out[o]);
    }
}

// ---------------------------------------------------------------------------
// R25 WIDE gemm (level 1 only): block covers 256 rows x FULL N=128 (both
// n-halves). Rationale: gemm1's stage period ~6700 cyc holds only ~2500 cyc
// of MFMA-pipe work (2 waves/SIMD); the ~4200 cyc remainder proved
// insensitive to occupancy (R16), counted vmcnt (R18), no-LDS (R20), and
// phase-split+setprio (R21) => treat it as fixed per-stage cost and AMORTIZE:
// 2x MFMA per stage (128/wave), 32 KB W chunk, 2-slot 64 KB LDS ring, one
// 512-block round instead of two. Schedule = proven minimum-2-phase template
// (T3 recipe): {issue next-stage gl_lds; compute current from LDS; vmcnt(0);
// barrier}. Ring-2 safety: slot (t+1)&1's previous readers (stage t-1)
// finished at the barrier ending iter t-1, before iter t issues into it; the
// vmcnt(0) after compute guarantees stage t+1 landed (own wave) and the
// barrier publishes it cross-wave before iter t+1 reads. Load latency hides
// under the ~5000-cyc compute phase.
// Same S=16 split-K, same per-s K-order, same f16 partial rounding as the
// narrow kernel -> bit-identical partials -> absmax unchanged.
// acc = 4mt x 8nt x f32x4 = 128 VGPRs; launch_bounds(256,2) caps at 256
// (spill tripwire: WRITE_SIZE). 2 blocks/CU (LDS 64 KB and VGPR>128 agree).
// ---------------------------------------------------------------------------
template<int BI>
__launch_bounds__(256, 2)
__global__ void gemm_wide(const f16* __restrict__ hin, const int* __restrict__ ids,
                          const f16* __restrict__ Wf,
                          f16* __restrict__ part, int Mrows, int S)
{
    __shared__ f16 Wb[2][16384];        // 64 KB: 2-slot ring of 32 KB chunks

    const int tid  = threadIdx.x;
    const int lane = tid & 63;
    const int wv   = tid >> 6;                     // 0..3
    const int b    = blockIdx.x;
    const int s    = b & (S - 1);                  // S is pow2
    const int mb   = b >> 4;                       // S==16 for level 1 (asserted by launch)
    const int m0   = mb * 256;
    const int i0   = s * BI;
    const bool tail = (s == 1 || s == 2);
    const int itail = (s == 1) ? 128 : 129;

    const int mrow = lane & 15;
    const int q    = lane >> 4;
    const int wm   = wv * 64;

    // ---- r fragments (A-layout) for this wave's 64 rows ----
    f16x8 rf[4][4];
    int rowL[4];
    #pragma unroll
    for (int mt = 0; mt < 4; ++mt) {
        int p = m0 + wm + mt * 16 + mrow;
        int row = ids ? ids[2 * p + 1] : 2 * p + 1;
        rowL[mt] = ids ? ids[2 * p] : 2 * p;
        #pragma unroll
        for (int t = 0; t < 4; ++t)
            rf[mt][t] = *(const f16x8*)&hin[(size_t)row * DD + t * 32 + q * 8];
    }

    // ---- l-window: this lane's 4 rows, halves [i0, i0+BI) in registers ----
    f16 lw[4][BI];
    #pragma unroll
    for (int mt = 0; mt < 4; ++mt) {
        const f16* src = &hin[(size_t)rowL[mt] * DD + i0];
        if constexpr (BI == 8)      { *(f16x8*)&lw[mt][0] = *(const f16x8*)src; }
        else if constexpr (BI == 4) { *(unsigned long long*)&lw[mt][0] = *(const unsigned long long*)src; }
        else if constexpr (BI == 2) { *(unsigned int*)&lw[mt][0] = *(const unsigned int*)src; }
        else                        { lw[mt][0] = src[0]; }
    }

    // ---- async W staging: one FULL 32 KB chunk (both halves) -> ring slot ----
    // 32 j-subchunks split across 4 waves -> 8 global_load_lds per wave/stage
    auto stage = [&](int i, int slot) {
        const f16* g = Wf + (size_t)i * 16384;
        #pragma unroll
        for (int k = 0; k < 8; ++k) {
            int j = k * 4 + wv;                    // 0..31
            const f16* gg = g + (size_t)(j * 64 + lane) * 8;
            f16* l = &Wb[slot][(size_t)(j * 64) * 8];
            __builtin_amdgcn_global_load_lds(
                (const __attribute__((address_space(1))) unsigned int*)gg,
                (__attribute__((address_space(3))) unsigned int*)l, 16, 0, 0);
        }
    };

    // ---- prologue: stage 0, land, publish ----
    stage(i0, 0);
    wait_vmcnt<0>();
    __builtin_amdgcn_s_barrier();

    f32x4 acc[4][8] = {};

    // one t4-step on slot SLOT: A = lb*rf (kron) or rf (tail), B = 8 frags
#define TSTEP(T4, SLOT, KRON, LBV)                                                      \
    {                                                                                   \
        f16x8 a[4];                                                                     \
        _Pragma("unroll")                                                               \
        for (int mt = 0; mt < 4; ++mt)                                                  \
            a[mt] = (KRON) ? (LBV[mt] * rf[mt][T4]) : rf[mt][T4];                       \
        _Pragma("unroll")                                                               \
        for (int nt = 0; nt < 8; ++nt) {                                                \
            f16x8 wc = *(const f16x8*)&Wb[SLOT][nt * 2048 + (T4) * 512 + lane * 8];     \
            _Pragma("unroll")                                                           \
            for (int mt = 0; mt < 4; ++mt)                                              \
                acc[mt][nt] = __builtin_amdgcn_mfma_f32_16x16x32_f16(a[mt], wc, acc[mt][nt], 0, 0, 0); \
        }                                                                               \
    }

    #pragma unroll
    for (int ii = 0; ii < BI; ++ii) {
        // issue next stage into the other slot (tail stage = index BI)
        if (ii + 1 < BI)          stage(i0 + ii + 1, (ii + 1) & 1);
        else if (tail)            stage(itail, BI & 1);
        // broadcast l values for this i (static lw index)
        f16x8 lb[4];
        #pragma unroll
        for (int mt = 0; mt < 4; ++mt) {
            f16 v = lw[mt][ii];
            #pragma unroll
            for (int e = 0; e < 8; ++e) lb[mt][e] = v;
        }
        __builtin_amdgcn_s_setprio(1);
        TSTEP(0, ii & 1, true, lb); TSTEP(1, ii & 1, true, lb);
        TSTEP(2, ii & 1, true, lb); TSTEP(3, ii & 1, true, lb);
        __builtin_amdgcn_s_setprio(0);
        if (ii + 1 < BI || tail) {          // next stage landed + publish
            wait_vmcnt<0>();
            __builtin_amdgcn_s_barrier();
        }
    }

    if (tail) {
        constexpr int slot = BI & 1;
        if (s == 1) {       // lin-l: overwrite rf with l-row A-frags
            #pragma unroll
            for (int mt = 0; mt < 4; ++mt)
                #pragma unroll
                for (int t = 0; t < 4; ++t)
                    rf[mt][t] = *(const f16x8*)&hin[(size_t)rowL[mt] * DD + t * 32 + q * 8];
        }
        f16x8 dummy[4];
        __builtin_amdgcn_s_setprio(1);
        TSTEP(0, slot, false, dummy); TSTEP(1, slot, false, dummy);
        TSTEP(2, slot, false, dummy); TSTEP(3, slot, false, dummy);
        __builtin_amdgcn_s_setprio(0);
    }
#undef TSTEP

    // ---- store f16 partial tile (full 128 cols): col=lane&15, row=q*4+reg ----
    f16* pb = part + ((size_t)s * Mrows + m0) * DD;
    #pragma unroll
    for (int mt = 0; mt < 4; ++mt)
        #pragma unroll
        for (int nt = 0; nt < 8; ++nt) {
            int colg = nt * 16 + mrow;
            #pragma unroll
            for (int rr = 0; rr < 4; ++rr) {
                int rowl = wm + mt * 16 + q * 4 + rr;
                pb[(size_t)rowl * DD + colg] = (f16)acc[mt][nt][rr];
            }
        }
}

// ---------------------------------------------------------------------------
// NARROW gemm (levels 2-5): byte-exact R18 kernel — 4-slot 64 KB ring,
// counted-vmcnt d=3, per-stage barrier, nh XCD-pinning. 108 VGPR, proven.
// ---------------------------------------------------------------------------
template<int BI>
__launch_bounds__(256, 2)
__global__ void gemm_kernel(const f16* __restrict__ hin, const int* __restrict__ ids,
                            const f16* __restrict__ Wf,
                            f16* __restrict__ part, int Mrows, int S)
{
    __shared__ f16 Wb[4][8192];         // 64 KB: 4-slot ring of 16 KB chunks

    const int tid  = threadIdx.x;
    const int lane = tid & 63;
    const int wv   = tid >> 6;                     // 0..3
    const int b    = blockIdx.x;
    const int nh   = (b >> 2) & 1;                 // XCD-half -> n-half
    const int r    = ((b >> 3) << 2) | (b & 3);
    const int mb   = r / S;
    const int s    = r - mb * S;
    const int m0   = mb * 256;
    const int i0   = s * BI;
    const bool tail = (s == 1 || s == 2);
    const int itail = (s == 1) ? 128 : 129;

    const int mrow = lane & 15;
    const int q    = lane >> 4;
    const int wm   = wv * 64;

    // ---- r fragments (A-layout) for this wave's 64 rows ----
    f16x8 rf[4][4];
    int rowL[4];
    #pragma unroll
    for (int mt = 0; mt < 4; ++mt) {
        int p = m0 + wm + mt * 16 + mrow;
        int row = ids ? ids[2 * p + 1] : 2 * p + 1;
        rowL[mt] = ids ? ids[2 * p] : 2 * p;
        #pragma unroll
        for (int t = 0; t < 4; ++t)
            rf[mt][t] = *(const f16x8*)&hin[(size_t)row * DD + t * 32 + q * 8];
    }

    // ---- l-window: this lane's 4 rows, halves [i0, i0+BI) in registers ----
    f16 lw[4][BI];
    #pragma unroll
    for (int mt = 0; mt < 4; ++mt) {
        const f16* src = &hin[(size_t)rowL[mt] * DD + i0];
        if constexpr (BI == 8)      { *(f16x8*)&lw[mt][0] = *(const f16x8*)src; }
        else if constexpr (BI == 4) { *(unsigned long long*)&lw[mt][0] = *(const unsigned long long*)src; }
        else if constexpr (BI == 2) { *(unsigned int*)&lw[mt][0] = *(const unsigned int*)src; }
        else                        { lw[mt][0] = src[0]; }
    }

    // ---- async W staging: one (i, nh) 16 KB chunk -> ring slot ----
    auto stage = [&](int i, int slot) {
        const f16* g = Wf + (size_t)i * 16384 + nh * 8192;
        #pragma unroll
        for (int k = 0; k < 4; ++k) {
            int j = k * 4 + wv;                    // 0..15
            const f16* gg = g + (size_t)(j * 64 + lane) * 8;
            f16* l = &Wb[slot][(size_t)(j * 64) * 8];
            __builtin_amdgcn_global_load_lds(
                (const __attribute__((address_space(1))) unsigned int*)gg,
                (__attribute__((address_space(3))) unsigned int*)l, 16, 0, 0);
        }
    };

    // ---- prologue: fill pipeline 3 deep ----
    stage(i0, 0);
    stage(i0 + 1, 1);                              // BI >= 2 always
    if constexpr (BI >= 3) {
        stage(i0 + 2, 2);
        wait_vmcnt<8>();                           // stage 0 landed (own wave)
    } else {                                       // BI == 2: tail goes in prologue
        if (tail) stage(itail, 2);
        wait_vmcnt<4>();                           // stage 0 landed (own wave)
    }
    __builtin_amdgcn_s_barrier();                  // -> stage 0 landed, all waves

    f32x4 acc[4][4] = {};

#define TSTEP(T, SLOT, KRON, LBV)                                                       \
    {                                                                                   \
        f16x8 wc[4];                                                                    \
        _Pragma("unroll")                                                               \
        for (int nt = 0; nt < 4; ++nt)                                                  \
            wc[nt] = *(const f16x8*)&Wb[SLOT][nt * 2048 + (T) * 512 + lane * 8];        \
        _Pragma("unroll")                                                               \
        for (int mt = 0; mt < 4; ++mt) {                                                \
            f16x8 a = (KRON) ? (LBV[mt] * rf[mt][T]) : rf[mt][T];                       \
            _Pragma("unroll")                                                           \
            for (int nt = 0; nt < 4; ++nt)                                              \
                acc[mt][nt] = __builtin_amdgcn_mfma_f32_16x16x32_f16(a, wc[nt], acc[mt][nt], 0, 0, 0); \
        }                                                                               \
    }

    #pragma unroll
    for (int ii = 0; ii < BI; ++ii) {
        if constexpr (BI >= 3) {
            if (ii + 3 < BI)                stage(i0 + ii + 3, (ii + 3) & 3);
            else if (ii + 3 == BI && tail)  stage(itail, BI & 3);
        }
        if (ii <= BI - 4)       wait_vmcnt<8>();   // 2 stages in flight
        else if (ii == BI - 3)  wait_vmcnt<4>();   // 1 stage
        else                    wait_vmcnt<0>();   // last two iters: drain
        f16x8 lb[4];
        #pragma unroll
        for (int mt = 0; mt < 4; ++mt) {
            f16 v = lw[mt][ii];
            #pragma unroll
            for (int e = 0; e < 8; ++e) lb[mt][e] = v;
        }
        __builtin_amdgcn_s_setprio(1);
        TSTEP(0, ii & 3, true, lb); TSTEP(1, ii & 3, true, lb);
        TSTEP(2, ii & 3, true, lb); TSTEP(3, ii & 3, true, lb);
        __builtin_amdgcn_s_setprio(0);
        if (ii + 1 < BI || tail) __builtin_amdgcn_s_barrier();
    }

    if (tail) {
        constexpr int slot = (BI >= 3) ? (BI & 3) : 2;
        if (s == 1) {       // lin-l: overwrite rf with l-row A-frags
            #pragma unroll
            for (int mt = 0; mt < 4; ++mt)
                #pragma unroll
                for (int t = 0; t < 4; ++t)
                    rf[mt][t] = *(const f16x8*)&hin[(size_t)rowL[mt] * DD + t * 32 + q * 8];
        }
        f16x8 dummy[4];
        __builtin_amdgcn_s_setprio(1);
        TSTEP(0, slot, false, dummy); TSTEP(1, slot, false, dummy);
        TSTEP(2, slot, false, dummy); TSTEP(3, slot, false, dummy);
        __builtin_amdgcn_s_setprio(0);
    }
#undef TSTEP

    f16* pb = part + ((size_t)s * Mrows + m0) * DD + nh * 64;
    #pragma unroll
    for (int mt = 0; mt < 4; ++mt)
        #pragma unroll
        for (int nt = 0; nt < 4; ++nt) {
            int colg = nt * 16 + mrow;
            #pragma unroll
            for (int rr = 0; rr < 4; ++rr) {
                int rowl = wm + mt * 16 + q * 4 + rr;
                pb[(size_t)rowl * DD + colg] = (f16)acc[mt][nt][rr];
            }
        }
}

// ---------------------------------------------------------------------------
// level epilogue: h_out = f16(tanh(sum_s part[s] + bias))
// ---------------------------------------------------------------------------
__global__ void epi_level(const f16* __restrict__ part, const float* __restrict__ bias,
                          f16* __restrict__ hout, int Mrows, int S)
{
    int idx = (blockIdx.x * 256 + threadIdx.x) * 8;
    size_t stride = (size_t)Mrows * DD;
    float sum[8] = {};
    for (int s2 = 0; s2 < S; ++s2) {
        f16x8 v = *(const f16x8*)&part[(size_t)s2 * stride + idx];
        #pragma unroll
        for (int e = 0; e < 8; ++e) sum[e] += (float)v[e];
    }
    int n = idx & 127;
    f16x8 o;
    #pragma unroll
    for (int e = 0; e < 8; ++e) o[e] = (f16)tanhf(sum[e] + bias[n + e]);
    *(f16x8*)&hout[idx] = o;
}

// ---------------------------------------------------------------------------
// final epilogue: leaky_relu(sum_s part + bias) @ Wsm^T + bsm -> log_softmax
// ---------------------------------------------------------------------------
__global__ void fin_epi(const f16* __restrict__ part, const float* __restrict__ bias,
                        const float* __restrict__ Wsm_f, const float* __restrict__ bsm_f,
                        const unsigned short* __restrict__ wv_raw, void* __restrict__ outp, int S)
{
    int lane = threadIdx.x & 63;
    int wv = threadIdx.x >> 6;
    int p = blockIdx.x * 4 + wv;              // 0..511
    size_t stride = (size_t)512 * DD;
    const f16* base = part + (size_t)p * DD;
    float a0 = 0.f, a1 = 0.f;
    for (int s2 = 0; s2 < S; ++s2) {
        a0 += (float)base[(size_t)s2 * stride + lane];
        a1 += (float)base[(size_t)s2 * stride + 64 + lane];
    }
    a0 += bias[lane];      a1 += bias[64 + lane];
    a0 = (a0 > 0.f) ? a0 : 0.01f * a0;
    a1 = (a1 > 0.f) ? a1 : 0.01f * a1;
    float lg[NRELS];
    #pragma unroll
    for (int r = 0; r < NRELS; ++r) {
        float pr = a0 * Wsm_f[r * DD + lane] + a1 * Wsm_f[r * DD + 64 + lane];
        #pragma unroll
        for (int d = 1; d < 64; d <<= 1) pr += __shfl_xor(pr, d, 64);
        lg[r] = pr + bsm_f[r];
    }
    float mx = lg[0];
    #pragma unroll
    for (int r = 1; r < NRELS; ++r) mx = fmaxf(mx, lg[r]);
    float se = 0.f;
    #pragma unroll
    for (int r = 0; r < NRELS; ++r) se += expf(lg[r] - mx);
    float lse = logf(se) + mx;
    if (lane < NRELS) {
        float v = lg[lane] - lse;
        if (detect_bf(wv_raw)) ((__hip_bfloat16*)outp)[p * NRELS + lane] = __float2bfloat16(v);
        else                   ((float*)outp)[p * NRELS + lane] = v;
    }
}

// ---------------------------------------------------------------------------
extern "C" void kernel_launch(void* const* d_in, const int* in_sizes, int n_in,
                              void* d_out, int out_size, void* d_ws, size_t ws_size,
                              hipStream_t stream)
{
    const int* ids = (const int*)d_in[0];

    char* ws = (char*)d_ws;
    f16*   part     = (f16*)ws;                                      // 32 MiB region (f16 partials)
    f16*   h1       = (f16*)(ws + ((size_t)32 << 20));               // 2 MiB
    f16*   h2       = (f16*)(ws + ((size_t)34 << 20));               // 1 MiB
    f16*   h3       = (f16*)(ws + ((size_t)35 << 20));               // 0.5 MiB
    f16*   h4       = (f16*)(ws + ((size_t)35 << 20) + (512 << 10)); // 0.25 MiB
    f16*   WvT      = (f16*)(ws + ((size_t)36 << 20));               // 0.5 MiB
    f16*   Wext     = (f16*)(ws + ((size_t)36 << 20) + (512 << 10)); // 4.0625 MiB
    f16*   Wfin     = Wext + (size_t)NWF;                            // 4.0625 MiB
    float* bias_lvl = (float*)(Wfin + (size_t)NWF);
    float* bias_fin = bias_lvl + 128;
    float* Wsm_f    = bias_fin + 128;
    float* bsm_f    = Wsm_f + NRELS * DD;

    if (ws_size < ((size_t)48 << 20)) return;

    prep_all<<<2145, 256, 0, stream>>>(d_in[1], d_in[2], d_in[3], d_in[4], d_in[5], d_in[6],
                                       d_in[7], d_in[8], d_in[9], d_in[10], d_in[11], d_in[12],
                                       WvT, Wext, Wfin, bias_lvl, bias_fin, Wsm_f, bsm_f);

    // R25: level 1 uses the WIDE kernel (full-N blocks, 512 = one round);
    // levels 2-5 unchanged R18 narrow kernels.
    // level 1 (fused embed-gather): M=8192, 32 mtiles(256x128) x S=16 -> 512
    gemm_wide<8><<<512, 256, 0, stream>>>(WvT, ids, Wext, part, 8192, 16);
    epi_level<<<512, 256, 0, stream>>>(part, bias_lvl, h1, 8192, 16);
    // level 2: M=4096, 16 mtiles x S=16 x 2 -> 512
    gemm_kernel<8><<<512, 256, 0, stream>>>(h1, nullptr, Wext, part, 4096, 16);
    epi_level<<<256, 256, 0, stream>>>(part, bias_lvl, h2, 4096, 16);
    // level 3: M=2048, 8 mtiles x S=32 x 2 -> 512
    gemm_kernel<4><<<512, 256, 0, stream>>>(h2, nullptr, Wext, part, 2048, 32);
    epi_level<<<128, 256, 0, stream>>>(part, bias_lvl, h3, 2048, 32);
    // level 4: M=1024, 4 mtiles x S=32 x 2 -> 256
    gemm_kernel<4><<<256, 256, 0, stream>>>(h3, nullptr, Wext, part, 1024, 32);
    epi_level<<<64, 256, 0, stream>>>(part, bias_lvl, h4, 1024, 32);
    // final: M=512, 2 mtiles x S=64 x 2 -> 256
    gemm_kernel<2><<<256, 256, 0, stream>>>(h4, nullptr, Wfin, part, 512, 64);
    fin_epi<<<128, 256, 0, stream>>>(part, bias_fin, Wsm_f, bsm_f,
                                     (const unsigned short*)d_in[1], d_out, 64);
}

// Round 11
// 276.808 us; speedup vs baseline: 1.8232x; 1.1184x over previous
//
#include <hip/hip_runtime.h>
#include <hip/hip_bf16.h>
#include <hip/hip_fp16.h>

#define DD    128
#define VOCAB 2048
#define NRELS 7
#define NWF   (130 * 16384)   // W frag-layout elements: 128 kron + l + r chunks

typedef _Float16 f16;
typedef __attribute__((ext_vector_type(8))) _Float16 f16x8;
typedef __attribute__((ext_vector_type(4))) float    f32x4;

// flexible-dtype load: bf==1 -> bf16 storage, bf==0 -> f32 storage
__device__ __forceinline__ float lde(const void* p, size_t i, int bf) {
    if (bf) return (float)((const __hip_bfloat16*)p)[i];
    return ((const float*)p)[i];
}

// detect storage dtype by exponent-field sanity of Wv's first 64 uint16s
__device__ __forceinline__ int detect_bf(const unsigned short* wv) {
    int sane = 0;
    #pragma unroll
    for (int i = 0; i < 64; ++i) {
        unsigned e = (wv[i] >> 7) & 0xFFu;
        sane += (e >= 90u && e <= 160u) ? 1 : 0;
    }
    return sane == 64;
}

// counted vmcnt wait. N is a compile-time literal.
template<int N>
__device__ __forceinline__ void wait_vmcnt() {
    asm volatile("s_waitcnt vmcnt(%0)" :: "n"(N) : "memory");
}

// ---------------------------------------------------------------------------
// prep_all: WvT transpose, W frag-major repack (NT stores: write-once data),
// biases. Frag layout: Wf[((i*8+n8)*4+t)*512 + ln*8 + e] =
//                      W[n8*16+(ln&15)][i*128 + t*32 + (ln>>4)*8 + e]
// ---------------------------------------------------------------------------
__global__ void prep_all(const void* Wv, const void* bv,
                         const void* Wcps, const void* bcps,
                         const void* Wcpst, const void* bcpst,
                         const void* Wcpr, const void* bcpr,
                         const void* Wcprt, const void* bcprt,
                         const void* Wsm, const void* bsm,
                         f16* __restrict__ WvT, f16* __restrict__ Wext, f16* __restrict__ Wfin,
                         float* __restrict__ bias_lvl, float* __restrict__ bias_fin,
                         float* __restrict__ Wsm_f, float* __restrict__ bsm_f)
{
    const int bf = detect_bf((const unsigned short*)Wv);
    const int b = blockIdx.x;
    const int tid = threadIdx.x;

    if (b < 64) {                     // ---- WvT transpose ----
        __shared__ float tile[64][65];
        int vt = b >> 1, dt = b & 1;
        int tx = tid & 63, ty = tid >> 6;
        for (int yy = ty; yy < 64; yy += 4)
            tile[yy][tx] = lde(Wv, (size_t)(dt * 64 + yy) * VOCAB + vt * 64 + tx, bf);
        __syncthreads();
        for (int yy = ty; yy < 64; yy += 4) {
            int v = vt * 64 + yy, d = dt * 64 + tx;
            __builtin_nontemporal_store((f16)(tile[tx][yy] + lde(bv, d, bf)),
                                        &WvT[(size_t)v * DD + d]);
        }
        return;
    }
    if (b >= 2144) {                  // ---- biases + softmax weights ----
        if (tid < 128)      bias_lvl[tid] = lde(bcps, tid, bf) + lde(bcpst, tid, bf);
        else if (tid < 256) bias_fin[tid - 128] = lde(bcpr, tid - 128, bf) + lde(bcprt, tid - 128, bf);
        for (int o = tid; o < NRELS * DD; o += 256) Wsm_f[o] = lde(Wsm, o, bf);
        if (tid < NRELS) bsm_f[tid] = lde(bsm, tid, bf);
        return;
    }
    // ---- W frag repack ----
    const int bb    = b - 64;
    const int which = bb / 1040;      // 0: ext, 1: fin
    const int rem   = bb - which * 1040;
    const int i     = rem >> 3;       // 0..129
    const int n8    = rem & 7;
    const void* Wt = which ? (const void*)Wcprt : (const void*)Wcpst;
    const void* Ws = which ? (const void*)Wcpr  : (const void*)Wcps;
    f16* dst = which ? Wfin : Wext;

    __shared__ float tile[16 * 129];
    #pragma unroll
    for (int it = 0; it < 8; ++it) {
        int idx = it * 256 + tid;
        int rr = idx >> 7, c = idx & 127;
        float v = (i < 128) ? lde(Wt, (size_t)(n8 * 16 + rr) * 16384 + (size_t)i * 128 + c, bf)
                            : lde(Ws, (size_t)(n8 * 16 + rr) * 256 + (size_t)(i - 128) * 128 + c, bf);
        tile[rr * 129 + c] = v;
    }
    __syncthreads();
    f16* out = dst + (size_t)(i * 8 + n8) * 2048;
    #pragma unroll
    for (int it = 0; it < 8; ++it) {
        int o = it * 256 + tid;
        int t = o >> 9, ln = (o >> 3) & 63, e = o & 7;
        __builtin_nontemporal_store((f16)tile[(ln & 15) * 129 + t * 32 + ((ln >> 4) << 3) + e],
                                    &out[o]);
    }
}

// ---------------------------------------------------------------------------
// GEMM over A_ext = [kron(l,r) | l | r] vs W, split-K over kron rows i.
// Block = 256 threads = 4 waves x 64 rows -> 256-row x 64-col tile, sharing
// one 16 KB W chunk per stage through a FOUR-slot 64 KB LDS ring
// (global_load_lds). Body = the proven R18 kernel (counted-vmcnt d=3
// pipeline, per-stage s_barrier; 108 VGPR @ BI=8, zero spill, 259.6 us wall).
// R26: level 1 moves S=16->8 (BI=16): 512 blocks = ONE resident round
// (2 blocks/CU x 256 CU). Gains: total stage count -5.5%, one prologue fill
// per block instead of two rounds', level-1 partial traffic halved (gemm1
// WRITE 33->16.5 MB, epi1 read 33->16.5 MB), per-block rf/lw/C-store
// amortized over 2x work. Kernel body unchanged; BI==16 l-window path
// restored from R0. Session scorecard says the stage schedule itself is at
// its structural ceiling (R16/R18/R20/R21 null; R17/R23/R24/R25 regress) —
// this lever only reduces how many stages/blocks we pay for.
// Schedule: prefetch d=3, raw s_barrier every stage, steady vmcnt(8) =
// 2 stages x 4 loads/wave in flight across barriers. Race-safety as R18:
// wait at iter ii lands own stage-(ii+1); per-iter barrier publishes
// cross-wave; slot rewrite distance 3 on ring 4 crosses the consuming
// barrier; tail (slot BI&3) drained by vmcnt(0) at ii=BI-1 + barrier.
// launch_bounds(256,2): proven regalloc setting (tighter caps spill).
// XCD-pinned n-half (nh=(b>>2)&1). s==1 appends lin-l (i=128), s==2 lin-r
// (i=129). Partials f16 -> part[s][p][n].
// ---------------------------------------------------------------------------
template<int BI>
__launch_bounds__(256, 2)
__global__ void gemm_kernel(const f16* __restrict__ hin, const int* __restrict__ ids,
                            const f16* __restrict__ Wf,
                            f16* __restrict__ part, int Mrows, int S)
{
    __shared__ f16 Wb[4][8192];         // 64 KB: 4-slot ring of 16 KB chunks

    const int tid  = threadIdx.x;
    const int lane = tid & 63;
    const int wv   = tid >> 6;                     // 0..3
    const int b    = blockIdx.x;
    const int nh   = (b >> 2) & 1;                 // XCD-half -> n-half
    const int r    = ((b >> 3) << 2) | (b & 3);
    const int mb   = r / S;
    const int s    = r - mb * S;
    const int m0   = mb * 256;
    const int i0   = s * BI;
    const bool tail = (s == 1 || s == 2);
    const int itail = (s == 1) ? 128 : 129;

    const int mrow = lane & 15;
    const int q    = lane >> 4;
    const int wm   = wv * 64;

    // ---- r fragments (A-layout) for this wave's 64 rows ----
    f16x8 rf[4][4];
    int rowL[4];
    #pragma unroll
    for (int mt = 0; mt < 4; ++mt) {
        int p = m0 + wm + mt * 16 + mrow;
        int row = ids ? ids[2 * p + 1] : 2 * p + 1;
        rowL[mt] = ids ? ids[2 * p] : 2 * p;
        #pragma unroll
        for (int t = 0; t < 4; ++t)
            rf[mt][t] = *(const f16x8*)&hin[(size_t)row * DD + t * 32 + q * 8];
    }

    // ---- l-window: this lane's 4 rows, halves [i0, i0+BI) in registers ----
    f16 lw[4][BI];
    #pragma unroll
    for (int mt = 0; mt < 4; ++mt) {
        const f16* src = &hin[(size_t)rowL[mt] * DD + i0];
        if constexpr (BI == 16) { *(f16x8*)&lw[mt][0] = *(const f16x8*)src;
                                  *(f16x8*)&lw[mt][8] = *(const f16x8*)(src + 8); }
        else if constexpr (BI == 8) { *(f16x8*)&lw[mt][0] = *(const f16x8*)src; }
        else if constexpr (BI == 4) { *(unsigned long long*)&lw[mt][0] = *(const unsigned long long*)src; }
        else if constexpr (BI == 2) { *(unsigned int*)&lw[mt][0] = *(const unsigned int*)src; }
        else { lw[mt][0] = src[0]; }
    }

    // ---- async W staging: one (i, nh) 16 KB chunk -> ring slot ----
    // 16 j-subchunks split across 4 waves -> 4 global_load_lds per wave/stage
    auto stage = [&](int i, int slot) {
        const f16* g = Wf + (size_t)i * 16384 + nh * 8192;
        #pragma unroll
        for (int k = 0; k < 4; ++k) {
            int j = k * 4 + wv;                    // 0..15
            const f16* gg = g + (size_t)(j * 64 + lane) * 8;
            f16* l = &Wb[slot][(size_t)(j * 64) * 8];
            __builtin_amdgcn_global_load_lds(
                (const __attribute__((address_space(1))) unsigned int*)gg,
                (__attribute__((address_space(3))) unsigned int*)l, 16, 0, 0);
        }
    };

    // ---- prologue: fill pipeline 3 deep ----
    stage(i0, 0);
    stage(i0 + 1, 1);                              // BI >= 2 always
    if constexpr (BI >= 3) {
        stage(i0 + 2, 2);
        wait_vmcnt<8>();                           // stage 0 landed (own wave)
    } else {                                       // BI == 2: tail goes in prologue
        if (tail) stage(itail, 2);
        wait_vmcnt<4>();                           // stage 0 landed (own wave)
    }
    __builtin_amdgcn_s_barrier();                  // -> stage 0 landed, all waves

    f32x4 acc[4][4] = {};

#define TSTEP(T, SLOT, KRON, LBV)                                                       \
    {                                                                                   \
        f16x8 wc[4];                                                                    \
        _Pragma("unroll")                                                               \
        for (int nt = 0; nt < 4; ++nt)                                                  \
            wc[nt] = *(const f16x8*)&Wb[SLOT][nt * 2048 + (T) * 512 + lane * 8];        \
        _Pragma("unroll")                                                               \
        for (int mt = 0; mt < 4; ++mt) {                                                \
            f16x8 a = (KRON) ? (LBV[mt] * rf[mt][T]) : rf[mt][T];                       \
            _Pragma("unroll")                                                           \
            for (int nt = 0; nt < 4; ++nt)                                              \
                acc[mt][nt] = __builtin_amdgcn_mfma_f32_16x16x32_f16(a, wc[nt], acc[mt][nt], 0, 0, 0); \
        }                                                                               \
    }

    #pragma unroll
    for (int ii = 0; ii < BI; ++ii) {
        // prefetch 3 stages ahead into ring slot (ii+3)&3 (tail stage = BI)
        if constexpr (BI >= 3) {
            if (ii + 3 < BI)                stage(i0 + ii + 3, (ii + 3) & 3);
            else if (ii + 3 == BI && tail)  stage(itail, BI & 3);
        }
        // counted wait: guarantee own stage-(ii+1) loads landed; the barrier
        // below publishes that cross-wave for the next iteration's reads.
        if (ii <= BI - 4)       wait_vmcnt<8>();   // 2 stages in flight
        else if (ii == BI - 3)  wait_vmcnt<4>();   // 1 stage
        else                    wait_vmcnt<0>();   // last two iters: drain
        // broadcast l values for this i (static lw index)
        f16x8 lb[4];
        #pragma unroll
        for (int mt = 0; mt < 4; ++mt) {
            f16 v = lw[mt][ii];
            #pragma unroll
            for (int e = 0; e < 8; ++e) lb[mt][e] = v;
        }
        __builtin_amdgcn_s_setprio(1);
        TSTEP(0, ii & 3, true, lb); TSTEP(1, ii & 3, true, lb);
        TSTEP(2, ii & 3, true, lb); TSTEP(3, ii & 3, true, lb);
        __builtin_amdgcn_s_setprio(0);
        if (ii + 1 < BI || tail) __builtin_amdgcn_s_barrier();
    }

    if (tail) {
        // tail chunk fully landed: vmcnt(0) at ii=BI-1 in every wave, then
        // the barrier above -> cross-wave visible.
        constexpr int slot = (BI >= 3) ? (BI & 3) : 2;
        if (s == 1) {       // lin-l: overwrite rf with l-row A-frags
            #pragma unroll
            for (int mt = 0; mt < 4; ++mt)
                #pragma unroll
                for (int t = 0; t < 4; ++t)
                    rf[mt][t] = *(const f16x8*)&hin[(size_t)rowL[mt] * DD + t * 32 + q * 8];
        }
        f16x8 dummy[4];
        __builtin_amdgcn_s_setprio(1);
        TSTEP(0, slot, false, dummy); TSTEP(1, slot, false, dummy);
        TSTEP(2, slot, false, dummy); TSTEP(3, slot, false, dummy);
        __builtin_amdgcn_s_setprio(0);
    }
#undef TSTEP

    // ---- store f16 partial tile: C/D layout col=lane&15, row=q*4+reg ----
    f16* pb = part + ((size_t)s * Mrows + m0) * DD + nh * 64;
    #pragma unroll
    for (int mt = 0; mt < 4; ++mt)
        #pragma unroll
        for (int nt = 0; nt < 4; ++nt) {
            int colg = nt * 16 + mrow;
            #pragma unroll
            for (int rr = 0; rr < 4; ++rr) {
                int rowl = wm + mt * 16 + q * 4 + rr;
                pb[(size_t)rowl * DD + colg] = (f16)acc[mt][nt][rr];
            }
        }
}

// ---------------------------------------------------------------------------
// level epilogue: h_out = f16(tanh(sum_s part[s] + bias))
// ---------------------------------------------------------------------------
__global__ void epi_level(const f16* __restrict__ part, const float* __restrict__ bias,
                          f16* __restrict__ hout, int Mrows, int S)
{
    int idx = (blockIdx.x * 256 + threadIdx.x) * 8;
    size_t stride = (size_t)Mrows * DD;
    float sum[8] = {};
    for (int s2 = 0; s2 < S; ++s2) {
        f16x8 v = *(const f16x8*)&part[(size_t)s2 * stride + idx];
        #pragma unroll
        for (int e = 0; e < 8; ++e) sum[e] += (float)v[e];
    }
    int n = idx & 127;
    f16x8 o;
    #pragma unroll
    for (int e = 0; e < 8; ++e) o[e] = (f16)tanhf(sum[e] + bias[n + e]);
    *(f16x8*)&hout[idx] = o;
}

// ---------------------------------------------------------------------------
// final epilogue: leaky_relu(sum_s part + bias) @ Wsm^T + bsm -> log_softmax
// ---------------------------------------------------------------------------
__global__ void fin_epi(const f16* __restrict__ part, const float* __restrict__ bias,
                        const float* __restrict__ Wsm_f, const float* __restrict__ bsm_f,
                        const unsigned short* __restrict__ wv_raw, void* __restrict__ outp, int S)
{
    int lane = threadIdx.x & 63;
    int wv = threadIdx.x >> 6;
    int p = blockIdx.x * 4 + wv;              // 0..511
    size_t stride = (size_t)512 * DD;
    const f16* base = part + (size_t)p * DD;
    float a0 = 0.f, a1 = 0.f;
    for (int s2 = 0; s2 < S; ++s2) {
        a0 += (float)base[(size_t)s2 * stride + lane];
        a1 += (float)base[(size_t)s2 * stride + 64 + lane];
    }
    a0 += bias[lane];      a1 += bias[64 + lane];
    a0 = (a0 > 0.f) ? a0 : 0.01f * a0;
    a1 = (a1 > 0.f) ? a1 : 0.01f * a1;
    float lg[NRELS];
    #pragma unroll
    for (int r = 0; r < NRELS; ++r) {
        float pr = a0 * Wsm_f[r * DD + lane] + a1 * Wsm_f[r * DD + 64 + lane];
        #pragma unroll
        for (int d = 1; d < 64; d <<= 1) pr += __shfl_xor(pr, d, 64);
        lg[r] = pr + bsm_f[r];
    }
    float mx = lg[0];
    #pragma unroll
    for (int r = 1; r < NRELS; ++r) mx = fmaxf(mx, lg[r]);
    float se = 0.f;
    #pragma unroll
    for (int r = 0; r < NRELS; ++r) se += expf(lg[r] - mx);
    float lse = logf(se) + mx;
    if (lane < NRELS) {
        float v = lg[lane] - lse;
        if (detect_bf(wv_raw)) ((__hip_bfloat16*)outp)[p * NRELS + lane] = __float2bfloat16(v);
        else                   ((float*)outp)[p * NRELS + lane] = v;
    }
}

// ---------------------------------------------------------------------------
extern "C" void kernel_launch(void* const* d_in, const int* in_sizes, int n_in,
                              void* d_out, int out_size, void* d_ws, size_t ws_size,
                              hipStream_t stream)
{
    const int* ids = (const int*)d_in[0];

    char* ws = (char*)d_ws;
    f16*   part     = (f16*)ws;                                      // 32 MiB region (f16 partials)
    f16*   h1       = (f16*)(ws + ((size_t)32 << 20));               // 2 MiB
    f16*   h2       = (f16*)(ws + ((size_t)34 << 20));               // 1 MiB
    f16*   h3       = (f16*)(ws + ((size_t)35 << 20));               // 0.5 MiB
    f16*   h4       = (f16*)(ws + ((size_t)35 << 20) + (512 << 10)); // 0.25 MiB
    f16*   WvT      = (f16*)(ws + ((size_t)36 << 20));               // 0.5 MiB
    f16*   Wext     = (f16*)(ws + ((size_t)36 << 20) + (512 << 10)); // 4.0625 MiB
    f16*   Wfin     = Wext + (size_t)NWF;                            // 4.0625 MiB
    float* bias_lvl = (float*)(Wfin + (size_t)NWF);
    float* bias_fin = bias_lvl + 128;
    float* Wsm_f    = bias_fin + 128;
    float* bsm_f    = Wsm_f + NRELS * DD;

    if (ws_size < ((size_t)48 << 20)) return;

    prep_all<<<2145, 256, 0, stream>>>(d_in[1], d_in[2], d_in[3], d_in[4], d_in[5], d_in[6],
                                       d_in[7], d_in[8], d_in[9], d_in[10], d_in[11], d_in[12],
                                       WvT, Wext, Wfin, bias_lvl, bias_fin, Wsm_f, bsm_f);

    // R26 = R18 baseline + level-1 S=8/BI=16 (512 blocks = one resident round).
    // level 1 (fused embed-gather): M=8192, 32 mtiles(256) x S=8 x 2 nh -> 512
    gemm_kernel<16><<<512, 256, 0, stream>>>(WvT, ids, Wext, part, 8192, 8);
    epi_level<<<512, 256, 0, stream>>>(part, bias_lvl, h1, 8192, 8);
    // level 2: M=4096, 16 mtiles x S=16 x 2 -> 512
    gemm_kernel<8><<<512, 256, 0, stream>>>(h1, nullptr, Wext, part, 4096, 16);
    epi_level<<<256, 256, 0, stream>>>(part, bias_lvl, h2, 4096, 16);
    // level 3: M=2048, 8 mtiles x S=32 x 2 -> 512
    gemm_kernel<4><<<512, 256, 0, stream>>>(h2, nullptr, Wext, part, 2048, 32);
    epi_level<<<128, 256, 0, stream>>>(part, bias_lvl, h3, 2048, 32);
    // level 4: M=1024, 4 mtiles x S=32 x 2 -> 256
    gemm_kernel<4><<<256, 256, 0, stream>>>(h3, nullptr, Wext, part, 1024, 32);
    epi_level<<<64, 256, 0, stream>>>(part, bias_lvl, h4, 1024, 32);
    // final: M=512, 2 mtiles x S=64 x 2 -> 256
    gemm_kernel<2><<<256, 256, 0, stream>>>(h4, nullptr, Wfin, part, 512, 64);
    fin_epi<<<128, 256, 0, stream>>>(part, bias_fin, Wsm_f, bsm_f,
                                     (const unsigned short*)d_in[1], d_out, 64);
}

// Round 12
// 262.622 us; speedup vs baseline: 1.9217x; 1.0540x over previous
//
#include <hip/hip_runtime.h>
#include <hip/hip_bf16.h>
#include <hip/hip_fp16.h>

#define DD    128
#define VOCAB 2048
#define NRELS 7
#define NWF   (130 * 16384)   // W frag-layout elements: 128 kron + l + r chunks

typedef _Float16 f16;
typedef __attribute__((ext_vector_type(8))) _Float16 f16x8;
typedef __attribute__((ext_vector_type(4))) float    f32x4;

// flexible-dtype load: bf==1 -> bf16 storage, bf==0 -> f32 storage
__device__ __forceinline__ float lde(const void* p, size_t i, int bf) {
    if (bf) return (float)((const __hip_bfloat16*)p)[i];
    return ((const float*)p)[i];
}

// detect storage dtype by exponent-field sanity of Wv's first 64 uint16s
__device__ __forceinline__ int detect_bf(const unsigned short* wv) {
    int sane = 0;
    #pragma unroll
    for (int i = 0; i < 64; ++i) {
        unsigned e = (wv[i] >> 7) & 0xFFu;
        sane += (e >= 90u && e <= 160u) ? 1 : 0;
    }
    return sane == 64;
}

// counted vmcnt wait. N is a compile-time literal.
template<int N>
__device__ __forceinline__ void wait_vmcnt() {
    asm volatile("s_waitcnt vmcnt(%0)" :: "n"(N) : "memory");
}

// ---------------------------------------------------------------------------
// prep_all: WvT transpose, W frag-major repack (NT stores: write-once data),
// biases. Frag layout: Wf[((i*8+n8)*4+t)*512 + ln*8 + e] =
//                      W[n8*16+(ln&15)][i*128 + t*32 + (ln>>4)*8 + e]
// ---------------------------------------------------------------------------
__global__ void prep_all(const void* Wv, const void* bv,
                         const void* Wcps, const void* bcps,
                         const void* Wcpst, const void* bcpst,
                         const void* Wcpr, const void* bcpr,
                         const void* Wcprt, const void* bcprt,
                         const void* Wsm, const void* bsm,
                         f16* __restrict__ WvT, f16* __restrict__ Wext, f16* __restrict__ Wfin,
                         float* __restrict__ bias_lvl, float* __restrict__ bias_fin,
                         float* __restrict__ Wsm_f, float* __restrict__ bsm_f)
{
    const int bf = detect_bf((const unsigned short*)Wv);
    const int b = blockIdx.x;
    const int tid = threadIdx.x;

    if (b < 64) {                     // ---- WvT transpose ----
        __shared__ float tile[64][65];
        int vt = b >> 1, dt = b & 1;
        int tx = tid & 63, ty = tid >> 6;
        for (int yy = ty; yy < 64; yy += 4)
            tile[yy][tx] = lde(Wv, (size_t)(dt * 64 + yy) * VOCAB + vt * 64 + tx, bf);
        __syncthreads();
        for (int yy = ty; yy < 64; yy += 4) {
            int v = vt * 64 + yy, d = dt * 64 + tx;
            __builtin_nontemporal_store((f16)(tile[tx][yy] + lde(bv, d, bf)),
                                        &WvT[(size_t)v * DD + d]);
        }
        return;
    }
    if (b >= 2144) {                  // ---- biases + softmax weights ----
        if (tid < 128)      bias_lvl[tid] = lde(bcps, tid, bf) + lde(bcpst, tid, bf);
        else if (tid < 256) bias_fin[tid - 128] = lde(bcpr, tid - 128, bf) + lde(bcprt, tid - 128, bf);
        for (int o = tid; o < NRELS * DD; o += 256) Wsm_f[o] = lde(Wsm, o, bf);
        if (tid < NRELS) bsm_f[tid] = lde(bsm, tid, bf);
        return;
    }
    // ---- W frag repack ----
    const int bb    = b - 64;
    const int which = bb / 1040;      // 0: ext, 1: fin
    const int rem   = bb - which * 1040;
    const int i     = rem >> 3;       // 0..129
    const int n8    = rem & 7;
    const void* Wt = which ? (const void*)Wcprt : (const void*)Wcpst;
    const void* Ws = which ? (const void*)Wcpr  : (const void*)Wcps;
    f16* dst = which ? Wfin : Wext;

    __shared__ float tile[16 * 129];
    #pragma unroll
    for (int it = 0; it < 8; ++it) {
        int idx = it * 256 + tid;
        int rr = idx >> 7, c = idx & 127;
        float v = (i < 128) ? lde(Wt, (size_t)(n8 * 16 + rr) * 16384 + (size_t)i * 128 + c, bf)
                            : lde(Ws, (size_t)(n8 * 16 + rr) * 256 + (size_t)(i - 128) * 128 + c, bf);
        tile[rr * 129 + c] = v;
    }
    __syncthreads();
    f16* out = dst + (size_t)(i * 8 + n8) * 2048;
    #pragma unroll
    for (int it = 0; it < 8; ++it) {
        int o = it * 256 + tid;
        int t = o >> 9, ln = (o >> 3) & 63, e = o & 7;
        __builtin_nontemporal_store((f16)tile[(ln & 15) * 129 + t * 32 + ((ln >> 4) << 3) + e],
                                    &out[o]);
    }
}

// ---------------------------------------------------------------------------
// GEMM over A_ext = [kron(l,r) | l | r] vs W, split-K over kron rows i.
// Block = 256 threads = 4 waves x 64 rows -> 256-row x 64-col tile, sharing
// one 16 KB W chunk per stage through a FOUR-slot 64 KB LDS ring
// (global_load_lds). This is the verified-best R18 kernel (259.6 us wall,
// gemm1 47.6 us, 108 VGPR, zero spill, zero bank conflicts), restored after
// R26's BI=16 variant hit a codegen cliff (LDS 80 KB, 926K bank conflicts).
// Sweet spot is narrow: 108 VGPR / 64 KB LDS — R17/R25/R26 each broke it.
// Schedule: prefetch d=3 ahead, raw s_barrier every stage, steady-state
// wait vmcnt(8) = 2 stages x 4 loads/wave in flight ACROSS barriers.
// Race-safety: the wait at iter ii guarantees this wave's stage-(ii+1) loads
// landed; the per-iter s_barrier makes that cross-wave before any wave reads
// slot (ii+1)&3. Slot rewrite (distance 3, ring 4) always crosses the
// barrier following its consumption. Tail stage (index BI, slot BI&3) is
// issued at ii=BI-3 (BI>=3) or in the prologue (BI==2) and fully drained by
// the vmcnt(0) at ii=BI-1 + barrier before use.
// Session evidence (13 experiments): occupancy x2 null (R16), counted-vmcnt
// null vs __syncthreads (R18~R0), no-LDS -20% (R20), phase-split+setprio
// null (R21), wide-N and BI=16 spill (R25/R26), cross-block fusion
// net-negative via both fence (R23: L2-flush) and sc1 (R24: write-through)
// paths, cooperative launch not graph-capturable (R22). This structure is
// the measured optimum of the explored space.
// launch_bounds(256,2): proven regalloc setting (tighter caps spill).
// XCD-pinned n-half (nh=(b>>2)&1). s==1 appends lin-l (i=128), s==2 lin-r
// (i=129). Partials f16 -> part[s][p][n].
// ---------------------------------------------------------------------------
template<int BI>
__launch_bounds__(256, 2)
__global__ void gemm_kernel(const f16* __restrict__ hin, const int* __restrict__ ids,
                            const f16* __restrict__ Wf,
                            f16* __restrict__ part, int Mrows, int S)
{
    __shared__ f16 Wb[4][8192];         // 64 KB: 4-slot ring of 16 KB chunks

    const int tid  = threadIdx.x;
    const int lane = tid & 63;
    const int wv   = tid >> 6;                     // 0..3
    const int b    = blockIdx.x;
    const int nh   = (b >> 2) & 1;                 // XCD-half -> n-half
    const int r    = ((b >> 3) << 2) | (b & 3);
    const int mb   = r / S;
    const int s    = r - mb * S;
    const int m0   = mb * 256;
    const int i0   = s * BI;
    const bool tail = (s == 1 || s == 2);
    const int itail = (s == 1) ? 128 : 129;

    const int mrow = lane & 15;
    const int q    = lane >> 4;
    const int wm   = wv * 64;

    // ---- r fragments (A-layout) for this wave's 64 rows ----
    f16x8 rf[4][4];
    int rowL[4];
    #pragma unroll
    for (int mt = 0; mt < 4; ++mt) {
        int p = m0 + wm + mt * 16 + mrow;
        int row = ids ? ids[2 * p + 1] : 2 * p + 1;
        rowL[mt] = ids ? ids[2 * p] : 2 * p;
        #pragma unroll
        for (int t = 0; t < 4; ++t)
            rf[mt][t] = *(const f16x8*)&hin[(size_t)row * DD + t * 32 + q * 8];
    }

    // ---- l-window: this lane's 4 rows, halves [i0, i0+BI) in registers ----
    f16 lw[4][BI];
    #pragma unroll
    for (int mt = 0; mt < 4; ++mt) {
        const f16* src = &hin[(size_t)rowL[mt] * DD + i0];
        if constexpr (BI == 8)      { *(f16x8*)&lw[mt][0] = *(const f16x8*)src; }
        else if constexpr (BI == 4) { *(unsigned long long*)&lw[mt][0] = *(const unsigned long long*)src; }
        else if constexpr (BI == 2) { *(unsigned int*)&lw[mt][0] = *(const unsigned int*)src; }
        else                        { lw[mt][0] = src[0]; }
    }

    // ---- async W staging: one (i, nh) 16 KB chunk -> ring slot ----
    // 16 j-subchunks split across 4 waves -> 4 global_load_lds per wave/stage
    auto stage = [&](int i, int slot) {
        const f16* g = Wf + (size_t)i * 16384 + nh * 8192;
        #pragma unroll
        for (int k = 0; k < 4; ++k) {
            int j = k * 4 + wv;                    // 0..15
            const f16* gg = g + (size_t)(j * 64 + lane) * 8;
            f16* l = &Wb[slot][(size_t)(j * 64) * 8];
            __builtin_amdgcn_global_load_lds(
                (const __attribute__((address_space(1))) unsigned int*)gg,
                (__attribute__((address_space(3))) unsigned int*)l, 16, 0, 0);
        }
    };

    // ---- prologue: fill pipeline 3 deep ----
    stage(i0, 0);
    stage(i0 + 1, 1);                              // BI >= 2 always
    if constexpr (BI >= 3) {
        stage(i0 + 2, 2);
        wait_vmcnt<8>();                           // stage 0 landed (own wave)
    } else {                                       // BI == 2: tail goes in prologue
        if (tail) stage(itail, 2);
        wait_vmcnt<4>();                           // stage 0 landed (own wave)
    }
    __builtin_amdgcn_s_barrier();                  // -> stage 0 landed, all waves

    f32x4 acc[4][4] = {};

#define TSTEP(T, SLOT, KRON, LBV)                                                       \
    {                                                                                   \
        f16x8 wc[4];                                                                    \
        _Pragma("unroll")                                                               \
        for (int nt = 0; nt < 4; ++nt)                                                  \
            wc[nt] = *(const f16x8*)&Wb[SLOT][nt * 2048 + (T) * 512 + lane * 8];        \
        _Pragma("unroll")                                                               \
        for (int mt = 0; mt < 4; ++mt) {                                                \
            f16x8 a = (KRON) ? (LBV[mt] * rf[mt][T]) : rf[mt][T];                       \
            _Pragma("unroll")                                                           \
            for (int nt = 0; nt < 4; ++nt)                                              \
                acc[mt][nt] = __builtin_amdgcn_mfma_f32_16x16x32_f16(a, wc[nt], acc[mt][nt], 0, 0, 0); \
        }                                                                               \
    }

    #pragma unroll
    for (int ii = 0; ii < BI; ++ii) {
        // prefetch 3 stages ahead into ring slot (ii+3)&3 (tail stage = BI)
        if constexpr (BI >= 3) {
            if (ii + 3 < BI)                stage(i0 + ii + 3, (ii + 3) & 3);
            else if (ii + 3 == BI && tail)  stage(itail, BI & 3);
        }
        // counted wait: guarantee own stage-(ii+1) loads landed; the barrier
        // below publishes that cross-wave for the next iteration's reads.
        if (ii <= BI - 4)       wait_vmcnt<8>();   // 2 stages in flight
        else if (ii == BI - 3)  wait_vmcnt<4>();   // 1 stage
        else                    wait_vmcnt<0>();   // last two iters: drain
        // broadcast l values for this i (static lw index)
        f16x8 lb[4];
        #pragma unroll
        for (int mt = 0; mt < 4; ++mt) {
            f16 v = lw[mt][ii];
            #pragma unroll
            for (int e = 0; e < 8; ++e) lb[mt][e] = v;
        }
        __builtin_amdgcn_s_setprio(1);
        TSTEP(0, ii & 3, true, lb); TSTEP(1, ii & 3, true, lb);
        TSTEP(2, ii & 3, true, lb); TSTEP(3, ii & 3, true, lb);
        __builtin_amdgcn_s_setprio(0);
        if (ii + 1 < BI || tail) __builtin_amdgcn_s_barrier();
    }

    if (tail) {
        // tail chunk fully landed: vmcnt(0) at ii=BI-1 in every wave, then
        // the barrier above -> cross-wave visible.
        constexpr int slot = (BI >= 3) ? (BI & 3) : 2;
        if (s == 1) {       // lin-l: overwrite rf with l-row A-frags
            #pragma unroll
            for (int mt = 0; mt < 4; ++mt)
                #pragma unroll
                for (int t = 0; t < 4; ++t)
                    rf[mt][t] = *(const f16x8*)&hin[(size_t)rowL[mt] * DD + t * 32 + q * 8];
        }
        f16x8 dummy[4];
        __builtin_amdgcn_s_setprio(1);
        TSTEP(0, slot, false, dummy); TSTEP(1, slot, false, dummy);
        TSTEP(2, slot, false, dummy); TSTEP(3, slot, false, dummy);
        __builtin_amdgcn_s_setprio(0);
    }
#undef TSTEP

    // ---- store f16 partial tile: C/D layout col=lane&15, row=q*4+reg ----
    f16* pb = part + ((size_t)s * Mrows + m0) * DD + nh * 64;
    #pragma unroll
    for (int mt = 0; mt < 4; ++mt)
        #pragma unroll
        for (int nt = 0; nt < 4; ++nt) {
            int colg = nt * 16 + mrow;
            #pragma unroll
            for (int rr = 0; rr < 4; ++rr) {
                int rowl = wm + mt * 16 + q * 4 + rr;
                pb[(size_t)rowl * DD + colg] = (f16)acc[mt][nt][rr];
            }
        }
}

// ---------------------------------------------------------------------------
// level epilogue: h_out = f16(tanh(sum_s part[s] + bias))
// ---------------------------------------------------------------------------
__global__ void epi_level(const f16* __restrict__ part, const float* __restrict__ bias,
                          f16* __restrict__ hout, int Mrows, int S)
{
    int idx = (blockIdx.x * 256 + threadIdx.x) * 8;
    size_t stride = (size_t)Mrows * DD;
    float sum[8] = {};
    for (int s2 = 0; s2 < S; ++s2) {
        f16x8 v = *(const f16x8*)&part[(size_t)s2 * stride + idx];
        #pragma unroll
        for (int e = 0; e < 8; ++e) sum[e] += (float)v[e];
    }
    int n = idx & 127;
    f16x8 o;
    #pragma unroll
    for (int e = 0; e < 8; ++e) o[e] = (f16)tanhf(sum[e] + bias[n + e]);
    *(f16x8*)&hout[idx] = o;
}

// ---------------------------------------------------------------------------
// final epilogue: leaky_relu(sum_s part + bias) @ Wsm^T + bsm -> log_softmax
// ---------------------------------------------------------------------------
__global__ void fin_epi(const f16* __restrict__ part, const float* __restrict__ bias,
                        const float* __restrict__ Wsm_f, const float* __restrict__ bsm_f,
                        const unsigned short* __restrict__ wv_raw, void* __restrict__ outp, int S)
{
    int lane = threadIdx.x & 63;
    int wv = threadIdx.x >> 6;
    int p = blockIdx.x * 4 + wv;              // 0..511
    size_t stride = (size_t)512 * DD;
    const f16* base = part + (size_t)p * DD;
    float a0 = 0.f, a1 = 0.f;
    for (int s2 = 0; s2 < S; ++s2) {
        a0 += (float)base[(size_t)s2 * stride + lane];
        a1 += (float)base[(size_t)s2 * stride + 64 + lane];
    }
    a0 += bias[lane];      a1 += bias[64 + lane];
    a0 = (a0 > 0.f) ? a0 : 0.01f * a0;
    a1 = (a1 > 0.f) ? a1 : 0.01f * a1;
    float lg[NRELS];
    #pragma unroll
    for (int r = 0; r < NRELS; ++r) {
        float pr = a0 * Wsm_f[r * DD + lane] + a1 * Wsm_f[r * DD + 64 + lane];
        #pragma unroll
        for (int d = 1; d < 64; d <<= 1) pr += __shfl_xor(pr, d, 64);
        lg[r] = pr + bsm_f[r];
    }
    float mx = lg[0];
    #pragma unroll
    for (int r = 1; r < NRELS; ++r) mx = fmaxf(mx, lg[r]);
    float se = 0.f;
    #pragma unroll
    for (int r = 0; r < NRELS; ++r) se += expf(lg[r] - mx);
    float lse = logf(se) + mx;
    if (lane < NRELS) {
        float v = lg[lane] - lse;
        if (detect_bf(wv_raw)) ((__hip_bfloat16*)outp)[p * NRELS + lane] = __float2bfloat16(v);
        else                   ((float*)outp)[p * NRELS + lane] = v;
    }
}

// ---------------------------------------------------------------------------
extern "C" void kernel_launch(void* const* d_in, const int* in_sizes, int n_in,
                              void* d_out, int out_size, void* d_ws, size_t ws_size,
                              hipStream_t stream)
{
    const int* ids = (const int*)d_in[0];

    char* ws = (char*)d_ws;
    f16*   part     = (f16*)ws;                                      // 32 MiB region (f16 partials)
    f16*   h1       = (f16*)(ws + ((size_t)32 << 20));               // 2 MiB
    f16*   h2       = (f16*)(ws + ((size_t)34 << 20));               // 1 MiB
    f16*   h3       = (f16*)(ws + ((size_t)35 << 20));               // 0.5 MiB
    f16*   h4       = (f16*)(ws + ((size_t)35 << 20) + (512 << 10)); // 0.25 MiB
    f16*   WvT      = (f16*)(ws + ((size_t)36 << 20));               // 0.5 MiB
    f16*   Wext     = (f16*)(ws + ((size_t)36 << 20) + (512 << 10)); // 4.0625 MiB
    f16*   Wfin     = Wext + (size_t)NWF;                            // 4.0625 MiB
    float* bias_lvl = (float*)(Wfin + (size_t)NWF);
    float* bias_fin = bias_lvl + 128;
    float* Wsm_f    = bias_fin + 128;
    float* bsm_f    = Wsm_f + NRELS * DD;

    if (ws_size < ((size_t)48 << 20)) return;

    prep_all<<<2145, 256, 0, stream>>>(d_in[1], d_in[2], d_in[3], d_in[4], d_in[5], d_in[6],
                                       d_in[7], d_in[8], d_in[9], d_in[10], d_in[11], d_in[12],
                                       WvT, Wext, Wfin, bias_lvl, bias_fin, Wsm_f, bsm_f);

    // R27 = exact R18 restoration (verified best: 259.6 us).
    // level 1 (fused embed-gather): M=8192, 32 mtiles(256) x S=16 x 2 nh -> 1024
    gemm_kernel<8><<<1024, 256, 0, stream>>>(WvT, ids, Wext, part, 8192, 16);
    epi_level<<<512, 256, 0, stream>>>(part, bias_lvl, h1, 8192, 16);
    // level 2: M=4096, 16 mtiles x S=16 x 2 -> 512
    gemm_kernel<8><<<512, 256, 0, stream>>>(h1, nullptr, Wext, part, 4096, 16);
    epi_level<<<256, 256, 0, stream>>>(part, bias_lvl, h2, 4096, 16);
    // level 3: M=2048, 8 mtiles x S=32 x 2 -> 512
    gemm_kernel<4><<<512, 256, 0, stream>>>(h2, nullptr, Wext, part, 2048, 32);
    epi_level<<<128, 256, 0, stream>>>(part, bias_lvl, h3, 2048, 32);
    // level 4: M=1024, 4 mtiles x S=32 x 2 -> 256
    gemm_kernel<4><<<256, 256, 0, stream>>>(h3, nullptr, Wext, part, 1024, 32);
    epi_level<<<64, 256, 0, stream>>>(part, bias_lvl, h4, 1024, 32);
    // final: M=512, 2 mtiles x S=64 x 2 -> 256
    gemm_kernel<2><<<256, 256, 0, stream>>>(h4, nullptr, Wfin, part, 512, 64);
    fin_epi<<<128, 256, 0, stream>>>(part, bias_fin, Wsm_f, bsm_f,
                                     (const unsigned short*)d_in[1], d_out, 64);
}